// Round 1
// baseline (23335.724 us; speedup 1.0000x reference)
//
#include <hip/hip_runtime.h>
#include <math.h>

// Problem constants
#define NBLK 6
#define NH 4
#define CCH 192
#define BB 2
#define SS 64
#define LL 256
#define DH 48
#define NP (BB*SS*LL)            // 32768 pixels
#define BUF ((size_t)NP*CCH)     // 6291456 floats per activation buffer

// ---------------- embedding + proj + rotary ----------------
// grid = NP blocks, 192 threads. X layout: (B,S,L,C) channel-last.
__global__ void embed_kernel(const int* __restrict__ tokens, const float* __restrict__ emb,
                             const float* __restrict__ proj_w, const float* __restrict__ proj_b,
                             float* __restrict__ X) {
    __shared__ float e[64];
    __shared__ float xr[CCH];
    int p = blockIdx.x;
    int tid = threadIdx.x;
    int tok = tokens[p];
    int l = p & (LL - 1);
    if (tid < 64) e[tid] = emb[tok * 64 + tid];
    __syncthreads();
    float acc = proj_b[tid];
    const float* wrow = proj_w + (size_t)tid * 64;
    #pragma unroll 8
    for (int k = 0; k < 64; ++k) acc += e[k] * wrow[k];
    xr[tid] = acc;
    __syncthreads();
    int j = tid % 96;
    // inv = 10000^(-2j/192) = exp(-(2j/192)*ln(10000))
    float inv = expf((float)(2 * j) * (-9.210340371976184f / 192.0f));
    float ang = (float)l * inv;
    float c = cosf(ang), s = sinf(ang);
    float part = (tid < 96) ? -xr[tid + 96] : xr[tid - 96];
    X[(size_t)p * CCH + tid] = xr[tid] * c + part * s;
}

// ---------------- per-pixel LayerNorm over C=192 ----------------
// one wave per pixel; block = 4 waves; grid = NP/4
__global__ __launch_bounds__(256) void ln_kernel(const float* __restrict__ X, float* __restrict__ Hn,
                                                 const float* __restrict__ g, const float* __restrict__ b) {
    int wave = threadIdx.x >> 6;
    int lane = threadIdx.x & 63;
    int p = blockIdx.x * 4 + wave;
    const float* xp = X + (size_t)p * CCH;
    float v0 = xp[lane], v1 = xp[lane + 64], v2 = xp[lane + 128];
    float s = v0 + v1 + v2;
    float q = v0 * v0 + v1 * v1 + v2 * v2;
    #pragma unroll
    for (int off = 32; off; off >>= 1) {
        s += __shfl_xor(s, off, 64);
        q += __shfl_xor(q, off, 64);
    }
    float mean = s * (1.0f / 192.0f);
    float var = q * (1.0f / 192.0f) - mean * mean;
    float r = rsqrtf(var + 1e-5f);
    float* hp = Hn + (size_t)p * CCH;
    hp[lane]       = (v0 - mean) * r * g[lane]       + b[lane];
    hp[lane + 64]  = (v1 - mean) * r * g[lane + 64]  + b[lane + 64];
    hp[lane + 128] = (v2 - mean) * r * g[lane + 128] + b[lane + 128];
}

// ---------------- generic fp32 GEMM: Out[m,n] = act(sum_k A[m,k]*W[n,k] + bias[n]) ----------------
// ACT: 0 none, 1 elu+1, 2 (elu+1)/sqrt(48), 3 exact gelu.  RES: accumulate into Out.
template<int ACT, bool RES>
__global__ __launch_bounds__(256) void mm_kernel(const float* __restrict__ A, const float* __restrict__ W,
                                                 const float* __restrict__ bias, float* __restrict__ Out,
                                                 int M, int N, int K) {
    __shared__ float As[16][65];
    __shared__ float Ws[16][65];
    int tidx = threadIdx.x & 15;   // n dir
    int tidy = threadIdx.x >> 4;   // m dir
    int n0 = blockIdx.x * 64;
    int m0 = blockIdx.y * 64;
    float acc[4][4] = {};
    int lk = threadIdx.x & 15, lr = threadIdx.x >> 4;
    for (int k0 = 0; k0 < K; k0 += 16) {
        #pragma unroll
        for (int i = 0; i < 4; ++i)
            As[lk][lr + i * 16] = A[(size_t)(m0 + lr + i * 16) * K + k0 + lk];
        #pragma unroll
        for (int i = 0; i < 4; ++i)
            Ws[lk][lr + i * 16] = W[(size_t)(n0 + lr + i * 16) * K + k0 + lk];
        __syncthreads();
        #pragma unroll
        for (int kk = 0; kk < 16; ++kk) {
            float a[4], w[4];
            #pragma unroll
            for (int i = 0; i < 4; ++i) a[i] = As[kk][tidy * 4 + i];
            #pragma unroll
            for (int j = 0; j < 4; ++j) w[j] = Ws[kk][tidx * 4 + j];
            #pragma unroll
            for (int i = 0; i < 4; ++i)
                #pragma unroll
                for (int j = 0; j < 4; ++j)
                    acc[i][j] += a[i] * w[j];
        }
        __syncthreads();
    }
    #pragma unroll
    for (int i = 0; i < 4; ++i) {
        int m = m0 + tidy * 4 + i;
        #pragma unroll
        for (int j = 0; j < 4; ++j) {
            int n = n0 + tidx * 4 + j;
            float v = acc[i][j] + bias[n];
            if (ACT == 1) v = (v > 0.f) ? v + 1.f : expf(v);                       // elu(v)+1
            if (ACT == 2) { v = (v > 0.f) ? v + 1.f : expf(v); v *= 0.14433756729740643f; } // /sqrt(48)
            if (ACT == 3) v = 0.5f * v * (1.0f + erff(v * 0.7071067811865475f));   // exact gelu
            size_t idx = (size_t)m * N + n;
            if (RES) Out[idx] += v; else Out[idx] = v;
        }
    }
}

// ---------------- linear attention core ----------------
// one block (256 thr) per (b, a, h) sequence. row_mode=1: A=S, N=L, stride=C.
// row_mode=0: A=L, N=S, stride=L*C.  Q already feature-mapped & scaled, K feature-mapped.
__global__ __launch_bounds__(256) void attn_kernel(const float* __restrict__ Q, const float* __restrict__ K,
                                                   const float* __restrict__ V, float* __restrict__ O,
                                                   int row_mode) {
    __shared__ float ks[64][DH + 1];
    __shared__ float vs[64][DH + 1];
    __shared__ float kvs[DH][DH + 1];
    __shared__ float ksums[DH];
    __shared__ float zs[64];
    int tid = threadIdx.x;
    int bid = blockIdx.x;
    int A = row_mode ? SS : LL;
    int h = bid & 3;
    int a = (bid >> 2) % A;
    int b = bid / (4 * A);
    size_t base, stride;
    int N;
    if (row_mode) { N = LL; stride = CCH;             base = ((size_t)(b * SS + a) * LL) * CCH + h * DH; }
    else          { N = SS; stride = (size_t)LL * CCH; base = ((size_t)(b * SS) * LL + a) * CCH + h * DH; }

    float kv[9];
    #pragma unroll
    for (int i = 0; i < 9; ++i) kv[i] = 0.f;
    float ksum = 0.f;

    // pass 1: kv = k^T v (48x48), ksum = sum_n k
    for (int n0 = 0; n0 < N; n0 += 64) {
        int cn = (N - n0 < 64) ? (N - n0) : 64;
        for (int idx = tid; idx < cn * DH; idx += 256) {
            int n = idx / DH, d = idx % DH;
            ks[n][d] = K[base + (size_t)(n0 + n) * stride + d];
            vs[n][d] = V[base + (size_t)(n0 + n) * stride + d];
        }
        __syncthreads();
        #pragma unroll
        for (int i = 0; i < 9; ++i) {
            int idx = tid + i * 256;     // 9*256 = 2304 = 48*48
            int d = idx / DH, e = idx % DH;
            float acc = kv[i];
            for (int n = 0; n < cn; ++n) acc += ks[n][d] * vs[n][e];
            kv[i] = acc;
        }
        if (tid < DH) {
            float s = 0.f;
            for (int n = 0; n < cn; ++n) s += ks[n][tid];
            ksum += s;
        }
        __syncthreads();
    }
    #pragma unroll
    for (int i = 0; i < 9; ++i) {
        int idx = tid + i * 256;
        kvs[idx / DH][idx % DH] = kv[i];
    }
    if (tid < DH) ksums[tid] = ksum;
    __syncthreads();

    // pass 2: o[n] = (q[n] @ kv) / (q[n]·ksum + 1e-6)
    for (int n0 = 0; n0 < N; n0 += 64) {
        int cn = (N - n0 < 64) ? (N - n0) : 64;
        for (int idx = tid; idx < cn * DH; idx += 256) {
            int n = idx / DH, d = idx % DH;
            ks[n][d] = Q[base + (size_t)(n0 + n) * stride + d];
        }
        __syncthreads();
        if (tid < cn) {
            float dot = 0.f;
            #pragma unroll
            for (int d = 0; d < DH; ++d) dot += ks[tid][d] * ksums[d];
            zs[tid] = 1.0f / (dot + 1e-6f);
        }
        __syncthreads();
        for (int idx = tid; idx < cn * DH; idx += 256) {
            int n = idx / DH, e = idx % DH;
            float acc = 0.f;
            #pragma unroll
            for (int d = 0; d < DH; ++d) acc += ks[n][d] * kvs[d][e];
            O[base + (size_t)(n0 + n) * stride + e] = acc * zs[n];
        }
        __syncthreads();
    }
}

// ---------------- final: sigmoid(softplus(out · pw_w + pw_b)) ----------------
__global__ __launch_bounds__(256) void final_kernel(const float* __restrict__ X, const float* __restrict__ pw_w,
                                                    const float* __restrict__ pw_b, float* __restrict__ out) {
    int wave = threadIdx.x >> 6;
    int lane = threadIdx.x & 63;
    int p = blockIdx.x * 4 + wave;
    const float* xp = X + (size_t)p * CCH;
    float s = xp[lane] * pw_w[lane] + xp[lane + 64] * pw_w[lane + 64] + xp[lane + 128] * pw_w[lane + 128];
    #pragma unroll
    for (int off = 32; off; off >>= 1) s += __shfl_xor(s, off, 64);
    if (lane == 0) {
        float o = s + pw_b[0];
        float e = expf(o);
        // sigmoid(softplus(o)) = (1+e^o)/(2+e^o) = 1 - 1/(2+e^o); e=inf -> 1
        out[p] = 1.0f - 1.0f / (2.0f + e);
    }
}

extern "C" void kernel_launch(void* const* d_in, const int* in_sizes, int n_in,
                              void* d_out, int out_size, void* d_ws, size_t ws_size,
                              hipStream_t stream) {
    const int*   tokens = (const int*)  d_in[0];
    const float* emb    = (const float*)d_in[1];
    const float* proj_w = (const float*)d_in[2];
    const float* proj_b = (const float*)d_in[3];
    const float* ln_g   = (const float*)d_in[4];
    const float* ln_b   = (const float*)d_in[5];
    const float* wq     = (const float*)d_in[6];
    const float* wk     = (const float*)d_in[7];
    const float* wv     = (const float*)d_in[8];
    const float* wo     = (const float*)d_in[9];
    const float* bq     = (const float*)d_in[10];
    const float* bk     = (const float*)d_in[11];
    const float* bv     = (const float*)d_in[12];
    const float* bo     = (const float*)d_in[13];
    const float* ffn_w1 = (const float*)d_in[14];
    const float* ffn_b1 = (const float*)d_in[15];
    const float* ffn_w2 = (const float*)d_in[16];
    const float* ffn_b2 = (const float*)d_in[17];
    const float* pw_w   = (const float*)d_in[18];
    const float* pw_b   = (const float*)d_in[19];

    float* X  = (float*)d_ws;        // residual stream (B,S,L,C)
    float* Hb = X  + BUF;            // LN output / attention O
    float* Qb = Hb + BUF;
    float* Kb = Qb + BUF;
    float* Vb = Kb + BUF;
    // FFN hidden (half of M at a time) aliases Qb..Kb: 16384*768 = 2*BUF floats

    embed_kernel<<<NP, CCH, 0, stream>>>(tokens, emb, proj_w, proj_b, X);

    for (int i = 0; i < NBLK; ++i) {
        for (int att = 0; att < 2; ++att) {
            const float* g  = ln_g + (size_t)(i * 3 + att) * CCH;
            const float* bn = ln_b + (size_t)(i * 3 + att) * CCH;
            ln_kernel<<<NP / 4, 256, 0, stream>>>(X, Hb, g, bn);
            size_t wi = (size_t)(i * 2 + att);
            const float* wqi = wq + wi * CCH * CCH;
            const float* wki = wk + wi * CCH * CCH;
            const float* wvi = wv + wi * CCH * CCH;
            const float* woi = wo + wi * CCH * CCH;
            const float* bqi = bq + wi * CCH;
            const float* bki = bk + wi * CCH;
            const float* bvi = bv + wi * CCH;
            const float* boi = bo + wi * CCH;
            dim3 g1(CCH / 64, NP / 64);   // (3, 512)
            mm_kernel<2, false><<<g1, 256, 0, stream>>>(Hb, wqi, bqi, Qb, NP, CCH, CCH);
            mm_kernel<1, false><<<g1, 256, 0, stream>>>(Hb, wki, bki, Kb, NP, CCH, CCH);
            mm_kernel<0, false><<<g1, 256, 0, stream>>>(Hb, wvi, bvi, Vb, NP, CCH, CCH);
            int nseq = (att == 0) ? BB * SS * NH : BB * LL * NH;
            attn_kernel<<<nseq, 256, 0, stream>>>(Qb, Kb, Vb, Hb, att == 0 ? 1 : 0);
            mm_kernel<0, true><<<g1, 256, 0, stream>>>(Hb, woi, boi, X, NP, CCH, CCH);
        }
        // FFN
        const float* g  = ln_g + (size_t)(i * 3 + 2) * CCH;
        const float* bn = ln_b + (size_t)(i * 3 + 2) * CCH;
        ln_kernel<<<NP / 4, 256, 0, stream>>>(X, Hb, g, bn);
        const float* w1 = ffn_w1 + (size_t)i * 768 * CCH;
        const float* b1 = ffn_b1 + (size_t)i * 768;
        const float* w2 = ffn_w2 + (size_t)i * CCH * 768;
        const float* b2 = ffn_b2 + (size_t)i * CCH;
        for (int half = 0; half < 2; ++half) {
            size_t m0 = (size_t)half * (NP / 2);
            float* hid = Qb;  // 2*BUF floats = (NP/2)*768
            dim3 gf1(768 / 64, (NP / 2) / 64);
            mm_kernel<3, false><<<gf1, 256, 0, stream>>>(Hb + m0 * CCH, w1, b1, hid, NP / 2, 768, CCH);
            dim3 gf2(CCH / 64, (NP / 2) / 64);
            mm_kernel<0, true><<<gf2, 256, 0, stream>>>(hid, w2, b2, X + m0 * CCH, NP / 2, CCH, 768);
        }
    }
    final_kernel<<<NP / 4, 256, 0, stream>>>(X, pw_w, pw_b, (float*)d_out);
}

// Round 2
// 6566.958 us; speedup vs baseline: 3.5535x; 3.5535x over previous
//
#include <hip/hip_runtime.h>
#include <math.h>

// Problem constants
#define NBLK 6
#define NH 4
#define CCH 192
#define BB 2
#define SS 64
#define LL 256
#define DH 48
#define NP (BB*SS*LL)            // 32768 pixels
#define BUF ((size_t)NP*CCH)     // 6291456 floats per activation buffer

// Attention-friendly permuted layouts (bijections on [0, NP*192)):
// mode 1 (row attn): (b, s, h, l, d)  -> seq = (b*64+s)*4+h, contiguous 256*48 per seq
// mode 2 (col attn): (b, l, h, s, d)  -> seq = (b*256+l)*4+h, contiguous 64*48 per seq
template<int MODE>
__device__ __forceinline__ size_t perm_idx(int m, int n) {
    int b = m >> 14;          // m / (64*256)
    int s = (m >> 8) & 63;
    int l = m & 255;
    int h = n / DH;
    int d = n - h * DH;
    if (MODE == 1) return (((size_t)((b * 64 + s) * 4 + h) * 256 + l) * DH + d);
    else           return (((size_t)((b * 256 + l) * 4 + h) * 64 + s) * DH + d);
}

// ---------------- embedding + proj + rotary ----------------
__global__ void embed_kernel(const int* __restrict__ tokens, const float* __restrict__ emb,
                             const float* __restrict__ proj_w, const float* __restrict__ proj_b,
                             float* __restrict__ X) {
    __shared__ float e[64];
    __shared__ float xr[CCH];
    int p = blockIdx.x;
    int tid = threadIdx.x;
    int tok = tokens[p];
    int l = p & (LL - 1);
    if (tid < 64) e[tid] = emb[tok * 64 + tid];
    __syncthreads();
    float acc = proj_b[tid];
    const float* wrow = proj_w + (size_t)tid * 64;
    #pragma unroll 8
    for (int k = 0; k < 64; ++k) acc += e[k] * wrow[k];
    xr[tid] = acc;
    __syncthreads();
    int j = tid % 96;
    float inv = expf((float)(2 * j) * (-9.210340371976184f / 192.0f));
    float ang = (float)l * inv;
    float c = cosf(ang), s = sinf(ang);
    float part = (tid < 96) ? -xr[tid + 96] : xr[tid - 96];
    X[(size_t)p * CCH + tid] = xr[tid] * c + part * s;
}

// ---------------- per-pixel LayerNorm over C=192 ----------------
__global__ __launch_bounds__(256) void ln_kernel(const float* __restrict__ X, float* __restrict__ Hn,
                                                 const float* __restrict__ g, const float* __restrict__ b) {
    int wave = threadIdx.x >> 6;
    int lane = threadIdx.x & 63;
    int p = blockIdx.x * 4 + wave;
    const float* xp = X + (size_t)p * CCH;
    float v0 = xp[lane], v1 = xp[lane + 64], v2 = xp[lane + 128];
    float s = v0 + v1 + v2;
    float q = v0 * v0 + v1 * v1 + v2 * v2;
    #pragma unroll
    for (int off = 32; off; off >>= 1) {
        s += __shfl_xor(s, off, 64);
        q += __shfl_xor(q, off, 64);
    }
    float mean = s * (1.0f / 192.0f);
    float var = q * (1.0f / 192.0f) - mean * mean;
    float r = rsqrtf(var + 1e-5f);
    float* hp = Hn + (size_t)p * CCH;
    hp[lane]       = (v0 - mean) * r * g[lane]       + b[lane];
    hp[lane + 64]  = (v1 - mean) * r * g[lane + 64]  + b[lane + 64];
    hp[lane + 128] = (v2 - mean) * r * g[lane + 128] + b[lane + 128];
}

// ---------------- generic fp32 GEMM: Out[m,n] = act(sum_k A[m,k]*W[n,k] + bias[n]) ----------------
// ACT: 0 none, 1 elu+1, 2 (elu+1)/sqrt(48), 3 exact gelu.  RES: accumulate into Out.
// OPERM: output index permutation (0 linear, 1 row-attn, 2 col-attn)
// IPERM: A-read index permutation (0 linear, 1 row-attn, 2 col-attn)
template<int ACT, bool RES, int OPERM, int IPERM>
__global__ __launch_bounds__(256) void mm_kernel(const float* __restrict__ A, const float* __restrict__ W,
                                                 const float* __restrict__ bias, float* __restrict__ Out,
                                                 int M, int N, int K) {
    __shared__ float As[16][65];
    __shared__ float Ws[16][65];
    int tidx = threadIdx.x & 15;   // n dir
    int tidy = threadIdx.x >> 4;   // m dir
    int n0 = blockIdx.x * 64;
    int m0 = blockIdx.y * 64;
    float acc[4][4] = {};
    int lk = threadIdx.x & 15, lr = threadIdx.x >> 4;
    for (int k0 = 0; k0 < K; k0 += 16) {
        #pragma unroll
        for (int i = 0; i < 4; ++i) {
            int m = m0 + lr + i * 16;
            size_t aidx = IPERM ? perm_idx<IPERM ? IPERM : 1>(m, k0 + lk) : ((size_t)m * K + k0 + lk);
            As[lk][lr + i * 16] = A[aidx];
        }
        #pragma unroll
        for (int i = 0; i < 4; ++i)
            Ws[lk][lr + i * 16] = W[(size_t)(n0 + lr + i * 16) * K + k0 + lk];
        __syncthreads();
        #pragma unroll
        for (int kk = 0; kk < 16; ++kk) {
            float a[4], w[4];
            #pragma unroll
            for (int i = 0; i < 4; ++i) a[i] = As[kk][tidy * 4 + i];
            #pragma unroll
            for (int j = 0; j < 4; ++j) w[j] = Ws[kk][tidx * 4 + j];
            #pragma unroll
            for (int i = 0; i < 4; ++i)
                #pragma unroll
                for (int j = 0; j < 4; ++j)
                    acc[i][j] += a[i] * w[j];
        }
        __syncthreads();
    }
    #pragma unroll
    for (int i = 0; i < 4; ++i) {
        int m = m0 + tidy * 4 + i;
        #pragma unroll
        for (int j = 0; j < 4; ++j) {
            int n = n0 + tidx * 4 + j;
            float v = acc[i][j] + bias[n];
            if (ACT == 1) v = (v > 0.f) ? v + 1.f : expf(v);
            if (ACT == 2) { v = (v > 0.f) ? v + 1.f : expf(v); v *= 0.14433756729740643f; }
            if (ACT == 3) v = 0.5f * v * (1.0f + erff(v * 0.7071067811865475f));
            size_t idx = OPERM ? perm_idx<OPERM ? OPERM : 1>(m, n) : ((size_t)m * N + n);
            if (RES) Out[idx] += v; else Out[idx] = v;
        }
    }
}

// ---------------- linear attention core (sequence-contiguous layout) ----------------
// one block (256 thr) per sequence of N positions x 48 dims, data at blockIdx.x*N*48.
template<int N>
__global__ __launch_bounds__(256) void attn_kernel(const float* __restrict__ Q, const float* __restrict__ K,
                                                   const float* __restrict__ V, float* __restrict__ O) {
    __shared__ float ks[64][DH + 1];
    __shared__ float vs[64][DH + 1];
    __shared__ float kvs[DH][DH + 1];
    __shared__ float ksums[DH];
    __shared__ float zs[64];
    int tid = threadIdx.x;
    size_t base = (size_t)blockIdx.x * N * DH;

    float kv[9];
    #pragma unroll
    for (int i = 0; i < 9; ++i) kv[i] = 0.f;
    float ksum = 0.f;

    // pass 1: kv = k^T v (48x48), ksum = sum_n k
    for (int n0 = 0; n0 < N; n0 += 64) {
        #pragma unroll
        for (int i = 0; i < 12; ++i) {           // 12*256 = 3072 = 64*48
            int idx = tid + i * 256;
            int n = idx / DH, d = idx - n * DH;
            ks[n][d] = K[base + (size_t)n0 * DH + idx];
            vs[n][d] = V[base + (size_t)n0 * DH + idx];
        }
        __syncthreads();
        #pragma unroll
        for (int i = 0; i < 9; ++i) {            // 9*256 = 2304 = 48*48
            int idx = tid + i * 256;
            int d = idx / DH, e = idx - d * DH;
            float acc = kv[i];
            #pragma unroll 8
            for (int n = 0; n < 64; ++n) acc += ks[n][d] * vs[n][e];
            kv[i] = acc;
        }
        if (tid < DH) {
            float s = 0.f;
            #pragma unroll 8
            for (int n = 0; n < 64; ++n) s += ks[n][tid];
            ksum += s;
        }
        __syncthreads();
    }
    #pragma unroll
    for (int i = 0; i < 9; ++i) {
        int idx = tid + i * 256;
        int d = idx / DH, e = idx - d * DH;
        kvs[d][e] = kv[i];
    }
    if (tid < DH) ksums[tid] = ksum;
    __syncthreads();

    // pass 2: o[n] = (q[n] @ kv) / (q[n]·ksum + 1e-6)
    for (int n0 = 0; n0 < N; n0 += 64) {
        #pragma unroll
        for (int i = 0; i < 12; ++i) {
            int idx = tid + i * 256;
            int n = idx / DH, d = idx - n * DH;
            ks[n][d] = Q[base + (size_t)n0 * DH + idx];
        }
        __syncthreads();
        if (tid < 64) {
            float dot = 0.f;
            #pragma unroll
            for (int d = 0; d < DH; ++d) dot += ks[tid][d] * ksums[d];
            zs[tid] = 1.0f / (dot + 1e-6f);
        }
        __syncthreads();
        #pragma unroll
        for (int i = 0; i < 12; ++i) {
            int idx = tid + i * 256;
            int n = idx / DH, e = idx - n * DH;
            float acc = 0.f;
            #pragma unroll
            for (int d = 0; d < DH; ++d) acc += ks[n][d] * kvs[d][e];
            O[base + (size_t)n0 * DH + idx] = acc * zs[n];
        }
        __syncthreads();
    }
}

// ---------------- final: sigmoid(softplus(out · pw_w + pw_b)) ----------------
__global__ __launch_bounds__(256) void final_kernel(const float* __restrict__ X, const float* __restrict__ pw_w,
                                                    const float* __restrict__ pw_b, float* __restrict__ out) {
    int wave = threadIdx.x >> 6;
    int lane = threadIdx.x & 63;
    int p = blockIdx.x * 4 + wave;
    const float* xp = X + (size_t)p * CCH;
    float s = xp[lane] * pw_w[lane] + xp[lane + 64] * pw_w[lane + 64] + xp[lane + 128] * pw_w[lane + 128];
    #pragma unroll
    for (int off = 32; off; off >>= 1) s += __shfl_xor(s, off, 64);
    if (lane == 0) {
        float o = s + pw_b[0];
        float e = expf(o);
        out[p] = 1.0f - 1.0f / (2.0f + e);   // sigmoid(softplus(o))
    }
}

extern "C" void kernel_launch(void* const* d_in, const int* in_sizes, int n_in,
                              void* d_out, int out_size, void* d_ws, size_t ws_size,
                              hipStream_t stream) {
    const int*   tokens = (const int*)  d_in[0];
    const float* emb    = (const float*)d_in[1];
    const float* proj_w = (const float*)d_in[2];
    const float* proj_b = (const float*)d_in[3];
    const float* ln_g   = (const float*)d_in[4];
    const float* ln_b   = (const float*)d_in[5];
    const float* wq     = (const float*)d_in[6];
    const float* wk     = (const float*)d_in[7];
    const float* wv     = (const float*)d_in[8];
    const float* wo     = (const float*)d_in[9];
    const float* bq     = (const float*)d_in[10];
    const float* bk     = (const float*)d_in[11];
    const float* bv     = (const float*)d_in[12];
    const float* bo     = (const float*)d_in[13];
    const float* ffn_w1 = (const float*)d_in[14];
    const float* ffn_b1 = (const float*)d_in[15];
    const float* ffn_w2 = (const float*)d_in[16];
    const float* ffn_b2 = (const float*)d_in[17];
    const float* pw_w   = (const float*)d_in[18];
    const float* pw_b   = (const float*)d_in[19];

    float* X  = (float*)d_ws;        // residual stream (B,S,L,C)
    float* Hb = X  + BUF;            // LN output / attention O (perm layout)
    float* Qb = Hb + BUF;
    float* Kb = Qb + BUF;
    float* Vb = Kb + BUF;

    embed_kernel<<<NP, CCH, 0, stream>>>(tokens, emb, proj_w, proj_b, X);

    for (int i = 0; i < NBLK; ++i) {
        for (int att = 0; att < 2; ++att) {
            const float* g  = ln_g + (size_t)(i * 3 + att) * CCH;
            const float* bn = ln_b + (size_t)(i * 3 + att) * CCH;
            ln_kernel<<<NP / 4, 256, 0, stream>>>(X, Hb, g, bn);
            size_t wi = (size_t)(i * 2 + att);
            const float* wqi = wq + wi * CCH * CCH;
            const float* wki = wk + wi * CCH * CCH;
            const float* wvi = wv + wi * CCH * CCH;
            const float* woi = wo + wi * CCH * CCH;
            const float* bqi = bq + wi * CCH;
            const float* bki = bk + wi * CCH;
            const float* bvi = bv + wi * CCH;
            const float* boi = bo + wi * CCH;
            dim3 g1(CCH / 64, NP / 64);   // (3, 512)
            if (att == 0) {
                mm_kernel<2, false, 1, 0><<<g1, 256, 0, stream>>>(Hb, wqi, bqi, Qb, NP, CCH, CCH);
                mm_kernel<1, false, 1, 0><<<g1, 256, 0, stream>>>(Hb, wki, bki, Kb, NP, CCH, CCH);
                mm_kernel<0, false, 1, 0><<<g1, 256, 0, stream>>>(Hb, wvi, bvi, Vb, NP, CCH, CCH);
                attn_kernel<LL><<<BB * SS * NH, 256, 0, stream>>>(Qb, Kb, Vb, Hb);
                mm_kernel<0, true, 0, 1><<<g1, 256, 0, stream>>>(Hb, woi, boi, X, NP, CCH, CCH);
            } else {
                mm_kernel<2, false, 2, 0><<<g1, 256, 0, stream>>>(Hb, wqi, bqi, Qb, NP, CCH, CCH);
                mm_kernel<1, false, 2, 0><<<g1, 256, 0, stream>>>(Hb, wki, bki, Kb, NP, CCH, CCH);
                mm_kernel<0, false, 2, 0><<<g1, 256, 0, stream>>>(Hb, wvi, bvi, Vb, NP, CCH, CCH);
                attn_kernel<SS><<<BB * LL * NH, 256, 0, stream>>>(Qb, Kb, Vb, Hb);
                mm_kernel<0, true, 0, 2><<<g1, 256, 0, stream>>>(Hb, woi, boi, X, NP, CCH, CCH);
            }
        }
        // FFN
        const float* g  = ln_g + (size_t)(i * 3 + 2) * CCH;
        const float* bn = ln_b + (size_t)(i * 3 + 2) * CCH;
        ln_kernel<<<NP / 4, 256, 0, stream>>>(X, Hb, g, bn);
        const float* w1 = ffn_w1 + (size_t)i * 768 * CCH;
        const float* b1 = ffn_b1 + (size_t)i * 768;
        const float* w2 = ffn_w2 + (size_t)i * CCH * 768;
        const float* b2 = ffn_b2 + (size_t)i * CCH;
        for (int half = 0; half < 2; ++half) {
            size_t m0 = (size_t)half * (NP / 2);
            float* hid = Qb;  // (NP/2)*768 floats = 2*BUF
            dim3 gf1(768 / 64, (NP / 2) / 64);
            mm_kernel<3, false, 0, 0><<<gf1, 256, 0, stream>>>(Hb + m0 * CCH, w1, b1, hid, NP / 2, 768, CCH);
            dim3 gf2(CCH / 64, (NP / 2) / 64);
            mm_kernel<0, true, 0, 0><<<gf2, 256, 0, stream>>>(hid, w2, b2, X + m0 * CCH, NP / 2, CCH, 768);
        }
    }
    final_kernel<<<NP / 4, 256, 0, stream>>>(X, pw_w, pw_b, (float*)d_out);
}

// Round 3
// 2567.649 us; speedup vs baseline: 9.0884x; 2.5576x over previous
//
#include <hip/hip_runtime.h>
#include <hip/hip_bf16.h>
#include <math.h>

#define NBLK 6
#define NH 4
#define CCH 192
#define BB 2
#define SS 64
#define LL 256
#define DH 48
#define NP (BB*SS*LL)            // 32768 pixels
#define BUF ((size_t)NP*CCH)     // elems per full activation tensor

typedef __attribute__((ext_vector_type(8))) short short8;
typedef __attribute__((ext_vector_type(4))) float float4v;

__device__ __forceinline__ unsigned short f2b(float f) {
    union { float f; unsigned int u; } v; v.f = f;
    unsigned int r = v.u + 0x7FFF + ((v.u >> 16) & 1);
    return (unsigned short)(r >> 16);
}
__device__ __forceinline__ float b2f(unsigned short u) {
    union { unsigned int u; float f; } v; v.u = ((unsigned int)u) << 16;
    return v.f;
}
__device__ __forceinline__ void async_lds16(const void* g, void* l) {
    __builtin_amdgcn_global_load_lds(
        (const __attribute__((address_space(1))) unsigned int*)g,
        (__attribute__((address_space(3))) unsigned int*)l, 16, 0, 0);
}

// Attention-friendly permuted layouts (bijections on [0, NP*192)):
// mode 1 (row attn): (b, s, h, l, d); mode 2 (col attn): (b, l, h, s, d)
template<int MODE>
__device__ __forceinline__ size_t perm_idx(int m, int n) {
    int b = m >> 14;
    int s = (m >> 8) & 63;
    int l = m & 255;
    int h = n / DH;
    int d = n - h * DH;
    if (MODE == 1) return (((size_t)((b * 64 + s) * 4 + h) * 256 + l) * DH + d);
    else           return (((size_t)((b * 256 + l) * 4 + h) * 64 + s) * DH + d);
}

// ---------------- fp32 -> bf16 convert ----------------
__global__ void convert_kernel(const float* __restrict__ s, unsigned short* __restrict__ d, int n) {
    int i = blockIdx.x * 256 + threadIdx.x;
    if (i < n) d[i] = f2b(s[i]);
}

// ---------------- embedding gather ----------------
__global__ void gather_kernel(const int* __restrict__ tokens, const float* __restrict__ emb,
                              unsigned short* __restrict__ Eg) {
    int idx = blockIdx.x * 256 + threadIdx.x;   // NP*64
    int p = idx >> 6, c = idx & 63;
    Eg[idx] = f2b(emb[tokens[p] * 64 + c]);
}

// ---------------- rotary: X = rotary(Xt) ----------------
__global__ __launch_bounds__(256) void rotary_kernel(const float* __restrict__ Xt, float* __restrict__ X) {
    int wave = threadIdx.x >> 6;
    int lane = threadIdx.x & 63;
    int p = blockIdx.x * 4 + wave;
    int l = p & (LL - 1);
    const float* xp = Xt + (size_t)p * CCH;
    float* op = X + (size_t)p * CCH;
    #pragma unroll
    for (int i = 0; i < 3; ++i) {
        int c = lane + i * 64;
        int j = c % 96;
        float inv = expf((float)(2 * j) * (-9.210340371976184f / 192.0f));
        float ang = (float)l * inv;
        float part = (c < 96) ? -xp[c + 96] : xp[c - 96];
        op[c] = xp[c] * cosf(ang) + part * sinf(ang);
    }
}

// ---------------- per-pixel LayerNorm over C=192, bf16 out ----------------
__global__ __launch_bounds__(256) void ln_kernel(const float* __restrict__ X, unsigned short* __restrict__ Hn,
                                                 const float* __restrict__ g, const float* __restrict__ b) {
    int wave = threadIdx.x >> 6;
    int lane = threadIdx.x & 63;
    int p = blockIdx.x * 4 + wave;
    const float* xp = X + (size_t)p * CCH;
    float v0 = xp[lane], v1 = xp[lane + 64], v2 = xp[lane + 128];
    float s = v0 + v1 + v2;
    float q = v0 * v0 + v1 * v1 + v2 * v2;
    #pragma unroll
    for (int off = 32; off; off >>= 1) {
        s += __shfl_xor(s, off, 64);
        q += __shfl_xor(q, off, 64);
    }
    float mean = s * (1.0f / 192.0f);
    float var = q * (1.0f / 192.0f) - mean * mean;
    float r = rsqrtf(var + 1e-5f);
    unsigned short* hp = Hn + (size_t)p * CCH;
    hp[lane]       = f2b((v0 - mean) * r * g[lane]       + b[lane]);
    hp[lane + 64]  = f2b((v1 - mean) * r * g[lane + 64]  + b[lane + 64]);
    hp[lane + 128] = f2b((v2 - mean) * r * g[lane + 128] + b[lane + 128]);
}

// ---------------- bf16 MFMA GEMM: Out[m,n] = act(sum_k A[m,k]*W[n,k] + bias[n]) ----------------
// Tile 128(m) x 96(n), BK=64. 4 waves: wave (wm,wn) covers 64x48 = 4x3 frags of 16x16x32.
// LDS: fragment-region layout, 1KB per 16-row x 32-k tile; A regions [0,16), W regions [16,28).
// OUT: 0 = bf16 store (with OPERM), 1 = fp32 +=, 2 = fp32 store.
// ACT: 0 none, 1 elu+1, 2 (elu+1)/sqrt(48), 3 exact gelu. IPERM: A-read permutation.
template<int ACT, int OUT, int OPERM, int IPERM>
__global__ __launch_bounds__(256, 2) void mm_bf16(const unsigned short* __restrict__ A,
                                                  const unsigned short* __restrict__ W,
                                                  const float* __restrict__ bias,
                                                  void* __restrict__ OutV,
                                                  int M, int N, int K) {
    unsigned short* Ob = (unsigned short*)OutV;
    float* Of = (float*)OutV;
    __shared__ __align__(16) unsigned char lds[28672];
    const int tid = threadIdx.x;
    const int lane = tid & 63;
    const int w = tid >> 6;
    const int wm = w >> 1, wn = w & 1;
    const int m0 = blockIdx.y * 128;
    const int n0 = blockIdx.x * 96;
    const int q8 = (lane >> 4) << 3;    // quad*8 (k within 32)
    const int r15 = lane & 15;

    float4v acc[4][3];
    #pragma unroll
    for (int i = 0; i < 4; ++i)
        #pragma unroll
        for (int j = 0; j < 3; ++j)
            acc[i][j] = (float4v){0.f, 0.f, 0.f, 0.f};

    for (int k0 = 0; k0 < K; k0 += 64) {
        #pragma unroll
        for (int it = 0; it < 7; ++it) {
            int c = it * 4 + w;                     // 28 chunks of 1KB
            const unsigned short* gp;
            if (c < 16) {                           // A: chunk c -> rows [g*16,+16), k [s*32,+32)
                int g = c >> 1, s = c & 1;
                int m = m0 + g * 16 + r15;
                int k = k0 + s * 32 + q8;
                size_t gi = IPERM ? perm_idx<IPERM ? IPERM : 1>(m, k) : ((size_t)m * K + k);
                gp = A + gi;
            } else {                                // W
                int wc = c - 16;
                int g = wc >> 1, s = wc & 1;
                int n = n0 + g * 16 + r15;
                gp = W + (size_t)n * K + k0 + s * 32 + q8;
            }
            async_lds16(gp, lds + c * 1024);
        }
        __syncthreads();
        #pragma unroll
        for (int s = 0; s < 2; ++s) {
            short8 af[4], wf[3];
            #pragma unroll
            for (int i = 0; i < 4; ++i)
                af[i] = *(const short8*)(lds + (((wm * 4 + i) * 2 + s) << 10) + lane * 16);
            #pragma unroll
            for (int j = 0; j < 3; ++j)
                wf[j] = *(const short8*)(lds + 16384 + (((wn * 3 + j) * 2 + s) << 10) + lane * 16);
            #pragma unroll
            for (int i = 0; i < 4; ++i)
                #pragma unroll
                for (int j = 0; j < 3; ++j)
                    acc[i][j] = __builtin_amdgcn_mfma_f32_16x16x32_bf16(af[i], wf[j], acc[i][j], 0, 0, 0);
        }
        __syncthreads();
    }

    const int nb = n0 + wn * 48 + r15;
    const int mb = m0 + wm * 64 + ((lane >> 4) << 2);
    #pragma unroll
    for (int j = 0; j < 3; ++j) {
        int n = nb + j * 16;
        float bv = bias[n];
        #pragma unroll
        for (int i = 0; i < 4; ++i) {
            int mrow = mb + i * 16;
            #pragma unroll
            for (int r = 0; r < 4; ++r) {
                float v = acc[i][j][r] + bv;
                if (ACT == 1) v = (v > 0.f) ? v + 1.f : expf(v);
                if (ACT == 2) { v = (v > 0.f) ? v + 1.f : expf(v); v *= 0.14433756729740643f; }
                if (ACT == 3) v = 0.5f * v * (1.0f + erff(v * 0.7071067811865475f));
                int m = mrow + r;
                if (OUT == 1)      Of[(size_t)m * N + n] += v;
                else if (OUT == 2) Of[(size_t)m * N + n] = v;
                else {
                    size_t idx = OPERM ? perm_idx<OPERM ? OPERM : 1>(m, n) : ((size_t)m * N + n);
                    Ob[idx] = f2b(v);
                }
            }
        }
    }
}

// ---------------- linear attention core (sequence-contiguous bf16) ----------------
template<int N>
__global__ __launch_bounds__(256) void attn_kernel(const unsigned short* __restrict__ Q,
                                                   const unsigned short* __restrict__ K,
                                                   const unsigned short* __restrict__ V,
                                                   unsigned short* __restrict__ O) {
    __shared__ float ks[64][DH + 1];
    __shared__ float vs[64][DH + 1];
    __shared__ float kvs[DH][DH + 1];
    __shared__ float ksums[DH];
    __shared__ float zs[64];
    int tid = threadIdx.x;
    size_t base = (size_t)blockIdx.x * N * DH;
    const unsigned int* Qp = (const unsigned int*)(Q + base);
    const unsigned int* Kp = (const unsigned int*)(K + base);
    const unsigned int* Vp = (const unsigned int*)(V + base);
    unsigned int* Op = (unsigned int*)(O + base);

    float kv[9];
    #pragma unroll
    for (int i = 0; i < 9; ++i) kv[i] = 0.f;
    float ksum = 0.f;

    for (int n0 = 0; n0 < N; n0 += 64) {
        #pragma unroll
        for (int i = 0; i < 6; ++i) {              // 6*256 uints = 64*48 bf16
            int u = tid + i * 256;
            unsigned int kw = Kp[n0 * 24 + u];
            unsigned int vw = Vp[n0 * 24 + u];
            int n = u / 24, d = (u % 24) * 2;
            ks[n][d] = b2f((unsigned short)kw); ks[n][d + 1] = b2f((unsigned short)(kw >> 16));
            vs[n][d] = b2f((unsigned short)vw); vs[n][d + 1] = b2f((unsigned short)(vw >> 16));
        }
        __syncthreads();
        #pragma unroll
        for (int i = 0; i < 9; ++i) {              // 9*256 = 48*48
            int idx = tid + i * 256;
            int d = idx / DH, e = idx - d * DH;
            float acc = kv[i];
            #pragma unroll 8
            for (int n = 0; n < 64; ++n) acc += ks[n][d] * vs[n][e];
            kv[i] = acc;
        }
        if (tid < DH) {
            float s = 0.f;
            #pragma unroll 8
            for (int n = 0; n < 64; ++n) s += ks[n][tid];
            ksum += s;
        }
        __syncthreads();
    }
    #pragma unroll
    for (int i = 0; i < 9; ++i) {
        int idx = tid + i * 256;
        kvs[idx / DH][idx % DH] = kv[i];
    }
    if (tid < DH) ksums[tid] = ksum;
    __syncthreads();

    for (int n0 = 0; n0 < N; n0 += 64) {
        #pragma unroll
        for (int i = 0; i < 6; ++i) {
            int u = tid + i * 256;
            unsigned int qw = Qp[n0 * 24 + u];
            int n = u / 24, d = (u % 24) * 2;
            ks[n][d] = b2f((unsigned short)qw); ks[n][d + 1] = b2f((unsigned short)(qw >> 16));
        }
        __syncthreads();
        if (tid < 64) {
            float dot = 0.f;
            #pragma unroll
            for (int d = 0; d < DH; ++d) dot += ks[tid][d] * ksums[d];
            zs[tid] = 1.0f / (dot + 1e-6f);
        }
        __syncthreads();
        #pragma unroll
        for (int i = 0; i < 6; ++i) {
            int u = tid + i * 256;
            int n = u / 24, e = (u % 24) * 2;
            float a0 = 0.f, a1 = 0.f;
            #pragma unroll
            for (int d = 0; d < DH; ++d) {
                float q = ks[n][d];
                a0 += q * kvs[d][e];
                a1 += q * kvs[d][e + 1];
            }
            float z = zs[n];
            Op[n0 * 24 + u] = (unsigned int)f2b(a0 * z) | ((unsigned int)f2b(a1 * z) << 16);
        }
        __syncthreads();
    }
}

// ---------------- final: sigmoid(softplus(out · pw_w + pw_b)) ----------------
__global__ __launch_bounds__(256) void final_kernel(const float* __restrict__ X, const float* __restrict__ pw_w,
                                                    const float* __restrict__ pw_b, float* __restrict__ out) {
    int wave = threadIdx.x >> 6;
    int lane = threadIdx.x & 63;
    int p = blockIdx.x * 4 + wave;
    const float* xp = X + (size_t)p * CCH;
    float s = xp[lane] * pw_w[lane] + xp[lane + 64] * pw_w[lane + 64] + xp[lane + 128] * pw_w[lane + 128];
    #pragma unroll
    for (int off = 32; off; off >>= 1) s += __shfl_xor(s, off, 64);
    if (lane == 0) {
        float o = s + pw_b[0];
        float e = expf(o);
        out[p] = 1.0f - 1.0f / (2.0f + e);
    }
}

extern "C" void kernel_launch(void* const* d_in, const int* in_sizes, int n_in,
                              void* d_out, int out_size, void* d_ws, size_t ws_size,
                              hipStream_t stream) {
    const int*   tokens = (const int*)  d_in[0];
    const float* emb    = (const float*)d_in[1];
    const float* proj_w = (const float*)d_in[2];
    const float* proj_b = (const float*)d_in[3];
    const float* ln_g   = (const float*)d_in[4];
    const float* ln_b   = (const float*)d_in[5];
    const float* wq     = (const float*)d_in[6];
    const float* wk     = (const float*)d_in[7];
    const float* wv     = (const float*)d_in[8];
    const float* wo     = (const float*)d_in[9];
    const float* bq     = (const float*)d_in[10];
    const float* bk     = (const float*)d_in[11];
    const float* bv     = (const float*)d_in[12];
    const float* bo     = (const float*)d_in[13];
    const float* ffn_w1 = (const float*)d_in[14];
    const float* ffn_b1 = (const float*)d_in[15];
    const float* ffn_w2 = (const float*)d_in[16];
    const float* ffn_b2 = (const float*)d_in[17];
    const float* pw_w   = (const float*)d_in[18];
    const float* pw_b   = (const float*)d_in[19];

    // workspace layout
    float* X            = (float*)d_ws;              // 24 MB fp32 residual
    unsigned short* Hb  = (unsigned short*)(X + BUF);
    unsigned short* Qb  = Hb + BUF;
    unsigned short* Kb  = Qb + BUF;
    unsigned short* Vb  = Kb + BUF;
    unsigned short* hid = Vb + BUF;                  // 2*BUF bf16 (16384x768)
    unsigned short* Eg  = hid + 2 * BUF;             // NP*64 bf16
    unsigned short* wqb = Eg + (size_t)NP * 64;
    const int WSZ = NBLK * 2 * CCH * CCH;            // 442368
    const int FSZ = NBLK * 768 * CCH;                // 884736
    unsigned short* wkb = wqb + WSZ;
    unsigned short* wvb = wkb + WSZ;
    unsigned short* wob = wvb + WSZ;
    unsigned short* w1b = wob + WSZ;
    unsigned short* w2b = w1b + FSZ;
    unsigned short* pjb = w2b + FSZ;                 // 12288
    float* Xt = (float*)hid;                         // pre-rotary tmp (aliases hid, free at start)

    convert_kernel<<<(WSZ + 255) / 256, 256, 0, stream>>>(wq, wqb, WSZ);
    convert_kernel<<<(WSZ + 255) / 256, 256, 0, stream>>>(wk, wkb, WSZ);
    convert_kernel<<<(WSZ + 255) / 256, 256, 0, stream>>>(wv, wvb, WSZ);
    convert_kernel<<<(WSZ + 255) / 256, 256, 0, stream>>>(wo, wob, WSZ);
    convert_kernel<<<(FSZ + 255) / 256, 256, 0, stream>>>(ffn_w1, w1b, FSZ);
    convert_kernel<<<(FSZ + 255) / 256, 256, 0, stream>>>(ffn_w2, w2b, FSZ);
    convert_kernel<<<(12288 + 255) / 256, 256, 0, stream>>>(proj_w, pjb, 12288);

    gather_kernel<<<NP * 64 / 256, 256, 0, stream>>>(tokens, emb, Eg);
    mm_bf16<0, 2, 0, 0><<<dim3(2, 256), 256, 0, stream>>>(Eg, pjb, proj_b, Xt, NP, CCH, 64);
    rotary_kernel<<<NP / 4, 256, 0, stream>>>(Xt, X);

    for (int i = 0; i < NBLK; ++i) {
        for (int att = 0; att < 2; ++att) {
            const float* g  = ln_g + (size_t)(i * 3 + att) * CCH;
            const float* bn = ln_b + (size_t)(i * 3 + att) * CCH;
            ln_kernel<<<NP / 4, 256, 0, stream>>>(X, Hb, g, bn);
            size_t wi = (size_t)(i * 2 + att);
            const unsigned short* wqi = wqb + wi * CCH * CCH;
            const unsigned short* wki = wkb + wi * CCH * CCH;
            const unsigned short* wvi = wvb + wi * CCH * CCH;
            const unsigned short* woi = wob + wi * CCH * CCH;
            const float* bqi = bq + wi * CCH;
            const float* bki = bk + wi * CCH;
            const float* bvi = bv + wi * CCH;
            const float* boi = bo + wi * CCH;
            dim3 g1(2, 256);
            if (att == 0) {
                mm_bf16<2, 0, 1, 0><<<g1, 256, 0, stream>>>(Hb, wqi, bqi, Qb, NP, CCH, CCH);
                mm_bf16<1, 0, 1, 0><<<g1, 256, 0, stream>>>(Hb, wki, bki, Kb, NP, CCH, CCH);
                mm_bf16<0, 0, 1, 0><<<g1, 256, 0, stream>>>(Hb, wvi, bvi, Vb, NP, CCH, CCH);
                attn_kernel<LL><<<BB * SS * NH, 256, 0, stream>>>(Qb, Kb, Vb, Hb);
                mm_bf16<0, 1, 0, 1><<<g1, 256, 0, stream>>>(Hb, woi, boi, X, NP, CCH, CCH);
            } else {
                mm_bf16<2, 0, 2, 0><<<g1, 256, 0, stream>>>(Hb, wqi, bqi, Qb, NP, CCH, CCH);
                mm_bf16<1, 0, 2, 0><<<g1, 256, 0, stream>>>(Hb, wki, bki, Kb, NP, CCH, CCH);
                mm_bf16<0, 0, 2, 0><<<g1, 256, 0, stream>>>(Hb, wvi, bvi, Vb, NP, CCH, CCH);
                attn_kernel<SS><<<BB * LL * NH, 256, 0, stream>>>(Qb, Kb, Vb, Hb);
                mm_bf16<0, 1, 0, 2><<<g1, 256, 0, stream>>>(Hb, woi, boi, X, NP, CCH, CCH);
            }
        }
        // FFN
        const float* g  = ln_g + (size_t)(i * 3 + 2) * CCH;
        const float* bn = ln_b + (size_t)(i * 3 + 2) * CCH;
        ln_kernel<<<NP / 4, 256, 0, stream>>>(X, Hb, g, bn);
        const unsigned short* w1 = w1b + (size_t)i * 768 * CCH;
        const unsigned short* w2 = w2b + (size_t)i * CCH * 768;
        const float* b1 = ffn_b1 + (size_t)i * 768;
        const float* b2 = ffn_b2 + (size_t)i * CCH;
        for (int half = 0; half < 2; ++half) {
            size_t m0 = (size_t)half * (NP / 2);
            mm_bf16<3, 0, 0, 0><<<dim3(8, 128), 256, 0, stream>>>(Hb + m0 * CCH, w1, b1, hid, NP / 2, 768, CCH);
            mm_bf16<0, 1, 0, 0><<<dim3(2, 128), 256, 0, stream>>>(hid, w2, b2, X + m0 * CCH, NP / 2, CCH, 768);
        }
    }
    final_kernel<<<NP / 4, 256, 0, stream>>>(X, pw_w, pw_b, (float*)d_out);
}

// Round 4
// 2144.959 us; speedup vs baseline: 10.8793x; 1.1971x over previous
//
#include <hip/hip_runtime.h>
#include <hip/hip_bf16.h>
#include <math.h>

#define NBLK 6
#define NH 4
#define CCH 192
#define BB 2
#define SS 64
#define LL 256
#define DH 48
#define NP (BB*SS*LL)            // 32768 pixels
#define BUF ((size_t)NP*CCH)

typedef __attribute__((ext_vector_type(8))) short short8;
typedef __attribute__((ext_vector_type(4))) float float4v;

__device__ __forceinline__ unsigned short f2b(float f) {
    union { float f; unsigned int u; } v; v.f = f;
    unsigned int r = v.u + 0x7FFF + ((v.u >> 16) & 1);
    return (unsigned short)(r >> 16);
}
__device__ __forceinline__ float b2f(unsigned short u) {
    union { unsigned int u; float f; } v; v.u = ((unsigned int)u) << 16;
    return v.f;
}
__device__ __forceinline__ void async_lds16(const void* g, void* l) {
    __builtin_amdgcn_global_load_lds(
        (const __attribute__((address_space(1))) unsigned int*)g,
        (__attribute__((address_space(3))) unsigned int*)l, 16, 0, 0);
}

// n-major attention layouts (Q and O): mode 1 row (b,s,h,l,d); mode 2 col (b,l,h,s,d)
template<int MODE>
__device__ __forceinline__ size_t perm_idx(int m, int n) {
    int b = m >> 14;
    int s = (m >> 8) & 63;
    int l = m & 255;
    int h = n / DH;
    int d = n - h * DH;
    if (MODE == 1) return (((size_t)((b * 64 + s) * 4 + h) * 256 + l) * DH + d);
    else           return (((size_t)((b * 256 + l) * 4 + h) * 64 + s) * DH + d);
}

__global__ void convert_kernel(const float* __restrict__ s, unsigned short* __restrict__ d, int n) {
    int i = blockIdx.x * 256 + threadIdx.x;
    if (i < n) d[i] = f2b(s[i]);
}
__global__ void wqkv_concat(const float* __restrict__ wq, const float* __restrict__ wk,
                            const float* __restrict__ wv, unsigned short* __restrict__ d) {
    int idx = blockIdx.x * 256 + threadIdx.x;        // 12*576*192
    int wi = idx / (576 * CCH);
    int rem = idx - wi * 576 * CCH;
    int n = rem / CCH, k = rem - (rem / CCH) * CCH;
    int sg = n / 192, row = n - sg * 192;
    const float* src = (sg == 0) ? wq : (sg == 1) ? wk : wv;
    d[idx] = f2b(src[(size_t)wi * CCH * CCH + row * CCH + k]);
}
__global__ void bqkv_concat(const float* __restrict__ bq, const float* __restrict__ bk,
                            const float* __restrict__ bv, float* __restrict__ d) {
    int idx = blockIdx.x * 256 + threadIdx.x;        // 12*576
    if (idx >= NBLK * 2 * 576) return;
    int wi = idx / 576, n = idx - (idx / 576) * 576;
    int sg = n / 192, row = n - sg * 192;
    const float* src = (sg == 0) ? bq : (sg == 1) ? bk : bv;
    d[idx] = src[wi * CCH + row];
}

__global__ void gather_kernel(const int* __restrict__ tokens, const float* __restrict__ emb,
                              unsigned short* __restrict__ Eg) {
    int idx = blockIdx.x * 256 + threadIdx.x;   // NP*64
    int p = idx >> 6, c = idx & 63;
    Eg[idx] = f2b(emb[tokens[p] * 64 + c]);
}

__global__ __launch_bounds__(256) void rotary_kernel(const float* __restrict__ Xt, float* __restrict__ X) {
    int wave = threadIdx.x >> 6;
    int lane = threadIdx.x & 63;
    int p = blockIdx.x * 4 + wave;
    int l = p & (LL - 1);
    const float* xp = Xt + (size_t)p * CCH;
    float* op = X + (size_t)p * CCH;
    #pragma unroll
    for (int i = 0; i < 3; ++i) {
        int c = lane + i * 64;
        int j = c % 96;
        float inv = expf((float)(2 * j) * (-9.210340371976184f / 192.0f));
        float ang = (float)l * inv;
        float part = (c < 96) ? -xp[c + 96] : xp[c - 96];
        op[c] = xp[c] * cosf(ang) + part * sinf(ang);
    }
}

__global__ __launch_bounds__(256) void ln_kernel(const float* __restrict__ X, unsigned short* __restrict__ Hn,
                                                 const float* __restrict__ g, const float* __restrict__ b) {
    int wave = threadIdx.x >> 6;
    int lane = threadIdx.x & 63;
    int p = blockIdx.x * 4 + wave;
    const float* xp = X + (size_t)p * CCH;
    float v0 = xp[lane], v1 = xp[lane + 64], v2 = xp[lane + 128];
    float s = v0 + v1 + v2;
    float q = v0 * v0 + v1 * v1 + v2 * v2;
    #pragma unroll
    for (int off = 32; off; off >>= 1) {
        s += __shfl_xor(s, off, 64);
        q += __shfl_xor(q, off, 64);
    }
    float mean = s * (1.0f / 192.0f);
    float var = q * (1.0f / 192.0f) - mean * mean;
    float r = rsqrtf(var + 1e-5f);
    unsigned short* hp = Hn + (size_t)p * CCH;
    hp[lane]       = f2b((v0 - mean) * r * g[lane]       + b[lane]);
    hp[lane + 64]  = f2b((v1 - mean) * r * g[lane + 64]  + b[lane + 64]);
    hp[lane + 128] = f2b((v2 - mean) * r * g[lane + 128] + b[lane + 128]);
}

// Tile 128x96, BK=64. ATT=0 generic; ATT=1/2 fused QKV epilogue (N=576):
// seg0->Q(act (elu+1)/sqrt48, n-major), seg1->K(elu+1, d-major), seg2->V(d-major).
template<int ACT, int OUT, int OPERM, int IPERM, int ATT>
__global__ __launch_bounds__(256, 2) void mm_bf16(const unsigned short* __restrict__ A,
                                                  const unsigned short* __restrict__ W,
                                                  const float* __restrict__ bias,
                                                  void* __restrict__ OutV,
                                                  unsigned short* __restrict__ Qo,
                                                  unsigned short* __restrict__ Ko,
                                                  unsigned short* __restrict__ Vo,
                                                  int M, int N, int K) {
    unsigned short* Ob = (unsigned short*)OutV;
    float* Of = (float*)OutV;
    __shared__ __align__(16) unsigned char lds[28672];
    const int tid = threadIdx.x;
    const int lane = tid & 63;
    const int w = tid >> 6;
    const int wm = w >> 1, wn = w & 1;
    const int m0 = blockIdx.y * 128;
    const int n0 = blockIdx.x * 96;
    const int q8 = (lane >> 4) << 3;
    const int r15 = lane & 15;

    float4v acc[4][3];
    #pragma unroll
    for (int i = 0; i < 4; ++i)
        #pragma unroll
        for (int j = 0; j < 3; ++j)
            acc[i][j] = (float4v){0.f, 0.f, 0.f, 0.f};

    for (int k0 = 0; k0 < K; k0 += 64) {
        #pragma unroll
        for (int it = 0; it < 7; ++it) {
            int c = it * 4 + w;
            const unsigned short* gp;
            if (c < 16) {
                int g = c >> 1, s = c & 1;
                int m = m0 + g * 16 + r15;
                int k = k0 + s * 32 + q8;
                size_t gi = IPERM ? perm_idx<IPERM ? IPERM : 1>(m, k) : ((size_t)m * K + k);
                gp = A + gi;
            } else {
                int wc = c - 16;
                int g = wc >> 1, s = wc & 1;
                int n = n0 + g * 16 + r15;
                gp = W + (size_t)n * K + k0 + s * 32 + q8;
            }
            async_lds16(gp, lds + c * 1024);
        }
        __syncthreads();
        #pragma unroll
        for (int s = 0; s < 2; ++s) {
            short8 af[4], wf[3];
            #pragma unroll
            for (int i = 0; i < 4; ++i)
                af[i] = *(const short8*)(lds + (((wm * 4 + i) * 2 + s) << 10) + lane * 16);
            #pragma unroll
            for (int j = 0; j < 3; ++j)
                wf[j] = *(const short8*)(lds + 16384 + (((wn * 3 + j) * 2 + s) << 10) + lane * 16);
            #pragma unroll
            for (int i = 0; i < 4; ++i)
                #pragma unroll
                for (int j = 0; j < 3; ++j)
                    acc[i][j] = __builtin_amdgcn_mfma_f32_16x16x32_bf16(af[i], wf[j], acc[i][j], 0, 0, 0);
        }
        __syncthreads();
    }

    const int nb = n0 + wn * 48 + r15;
    const int mb = m0 + wm * 64 + ((lane >> 4) << 2);
    #pragma unroll
    for (int j = 0; j < 3; ++j) {
        int n = nb + j * 16;
        float bv = bias[n];
        if (ATT == 0) {
            #pragma unroll
            for (int i = 0; i < 4; ++i) {
                int mrow = mb + i * 16;
                #pragma unroll
                for (int r = 0; r < 4; ++r) {
                    float v = acc[i][j][r] + bv;
                    if (ACT == 1) v = (v > 0.f) ? v + 1.f : expf(v);
                    if (ACT == 2) { v = (v > 0.f) ? v + 1.f : expf(v); v *= 0.14433756729740643f; }
                    if (ACT == 3) v = 0.5f * v * (1.0f + erff(v * 0.7071067811865475f));
                    int m = mrow + r;
                    if (OUT == 1)      Of[(size_t)m * N + n] += v;
                    else if (OUT == 2) Of[(size_t)m * N + n] = v;
                    else {
                        size_t idx = OPERM ? perm_idx<OPERM ? OPERM : 1>(m, n) : ((size_t)m * N + n);
                        Ob[idx] = f2b(v);
                    }
                }
            }
        } else {
            const int Ns = (ATT == 1) ? 256 : 64;
            int sg = n / 192;
            int nn = n - sg * 192;
            int h = nn / DH;
            int d = nn - h * DH;
            #pragma unroll
            for (int i = 0; i < 4; ++i) {
                int mrow = mb + i * 16;
                #pragma unroll
                for (int r = 0; r < 4; ++r) {
                    int m = mrow + r;
                    int b = m >> 14, s = (m >> 8) & 63, l = m & 255;
                    int seq  = (ATT == 1) ? ((b * 64 + s) * 4 + h) : ((b * 256 + l) * 4 + h);
                    int npos = (ATT == 1) ? l : s;
                    float v = acc[i][j][r] + bv;
                    if (sg == 0) {
                        v = (v > 0.f) ? v + 1.f : expf(v);
                        v *= 0.14433756729740643f;
                        Qo[((size_t)seq * Ns + npos) * DH + d] = f2b(v);
                    } else if (sg == 1) {
                        v = (v > 0.f) ? v + 1.f : expf(v);
                        Ko[(size_t)seq * Ns * DH + (size_t)d * Ns + npos] = f2b(v);
                    } else {
                        Vo[(size_t)seq * Ns * DH + (size_t)d * Ns + npos] = f2b(v);
                    }
                }
            }
        }
    }
}

// MFMA linear attention, one wave per sequence.
// Q: [seq][n][d]; Kt,Vt: [seq][d][n]; O: [seq][n][e].
template<int N>
__global__ __launch_bounds__(256) void attn_mfma(const unsigned short* __restrict__ Q,
                                                 const unsigned short* __restrict__ Kt,
                                                 const unsigned short* __restrict__ Vt,
                                                 unsigned short* __restrict__ O) {
    __shared__ unsigned short kvs[4][48 * 72];
    __shared__ float zsh[4][N];
    __shared__ float ksums[4][48];
    const int lane = threadIdx.x & 63;
    const int w = threadIdx.x >> 6;
    const int seq = blockIdx.x * 4 + w;
    const int q = lane >> 4, r15 = lane & 15, q8 = q * 8;
    const unsigned short* kb = Kt + (size_t)seq * N * DH;
    const unsigned short* vb = Vt + (size_t)seq * N * DH;
    const unsigned short* qb = Q + (size_t)seq * N * DH;
    unsigned short* ob = O + (size_t)seq * N * DH;

    float4v kv[3][3];
    #pragma unroll
    for (int i = 0; i < 3; ++i)
        #pragma unroll
        for (int j = 0; j < 3; ++j)
            kv[i][j] = (float4v){0.f, 0.f, 0.f, 0.f};
    for (int ks = 0; ks < N; ks += 32) {
        short8 af[3], bf[3];
        #pragma unroll
        for (int t = 0; t < 3; ++t) {
            af[t] = *(const short8*)(kb + (size_t)(t * 16 + r15) * N + ks + q8);
            bf[t] = *(const short8*)(vb + (size_t)(t * 16 + r15) * N + ks + q8);
        }
        #pragma unroll
        for (int i = 0; i < 3; ++i)
            #pragma unroll
            for (int j = 0; j < 3; ++j)
                kv[i][j] = __builtin_amdgcn_mfma_f32_16x16x32_bf16(af[i], bf[j], kv[i][j], 0, 0, 0);
    }
    if (lane < 48) {
        float s = 0.f;
        const unsigned short* kr = kb + (size_t)lane * N;
        float acc = 0.f;
        for (int n = 0; n < N; n += 8) {
            short8 v = *(const short8*)(kr + n);
            #pragma unroll
            for (int e = 0; e < 8; ++e) acc += b2f((unsigned short)v[e]);
        }
        ksums[w][lane] = acc + s;
    }
    #pragma unroll
    for (int i = 0; i < 3; ++i)
        #pragma unroll
        for (int j = 0; j < 3; ++j)
            #pragma unroll
            for (int r = 0; r < 4; ++r) {
                int d = i * 16 + q * 4 + r, e = j * 16 + r15;
                kvs[w][e * 72 + d] = f2b(kv[i][j][r]);
            }
    #pragma unroll
    for (int ii = 0; ii < 12; ++ii) {
        int idx = lane + ii * 64;
        int e = idx >> 4, dd = 48 + (idx & 15);
        kvs[w][e * 72 + dd] = 0;
    }
    __syncthreads();
    for (int n = lane; n < N; n += 64) {
        const unsigned short* qr = qb + (size_t)n * DH;
        float dot = 0.f;
        #pragma unroll
        for (int d = 0; d < DH; ++d) dot += b2f(qr[d]) * ksums[w][d];
        zsh[w][n] = 1.0f / (dot + 1e-6f);
    }
    __syncthreads();
    short8 bkv[2][3];
    #pragma unroll
    for (int kk = 0; kk < 2; ++kk)
        #pragma unroll
        for (int t = 0; t < 3; ++t)
            bkv[kk][t] = *(const short8*)(&kvs[w][(t * 16 + r15) * 72 + kk * 32 + q8]);
    for (int mt = 0; mt < N / 16; ++mt) {
        float4v o[3];
        #pragma unroll
        for (int t = 0; t < 3; ++t) o[t] = (float4v){0.f, 0.f, 0.f, 0.f};
        #pragma unroll
        for (int kk = 0; kk < 2; ++kk) {
            short8 aq = *(const short8*)(qb + (size_t)(mt * 16 + r15) * DH + kk * 32 + q8);
            #pragma unroll
            for (int t = 0; t < 3; ++t)
                o[t] = __builtin_amdgcn_mfma_f32_16x16x32_bf16(aq, bkv[kk][t], o[t], 0, 0, 0);
        }
        float4v zv = *(const float4v*)(&zsh[w][mt * 16 + q * 4]);
        #pragma unroll
        for (int t = 0; t < 3; ++t)
            #pragma unroll
            for (int r = 0; r < 4; ++r)
                ob[(size_t)(mt * 16 + q * 4 + r) * DH + t * 16 + r15] = f2b(o[t][r] * zv[r]);
    }
}

__global__ __launch_bounds__(256) void final_kernel(const float* __restrict__ X, const float* __restrict__ pw_w,
                                                    const float* __restrict__ pw_b, float* __restrict__ out) {
    int wave = threadIdx.x >> 6;
    int lane = threadIdx.x & 63;
    int p = blockIdx.x * 4 + wave;
    const float* xp = X + (size_t)p * CCH;
    float s = xp[lane] * pw_w[lane] + xp[lane + 64] * pw_w[lane + 64] + xp[lane + 128] * pw_w[lane + 128];
    #pragma unroll
    for (int off = 32; off; off >>= 1) s += __shfl_xor(s, off, 64);
    if (lane == 0) {
        float o = s + pw_b[0];
        float e = expf(o);
        out[p] = 1.0f - 1.0f / (2.0f + e);
    }
}

extern "C" void kernel_launch(void* const* d_in, const int* in_sizes, int n_in,
                              void* d_out, int out_size, void* d_ws, size_t ws_size,
                              hipStream_t stream) {
    const int*   tokens = (const int*)  d_in[0];
    const float* emb    = (const float*)d_in[1];
    const float* proj_w = (const float*)d_in[2];
    const float* proj_b = (const float*)d_in[3];
    const float* ln_g   = (const float*)d_in[4];
    const float* ln_b   = (const float*)d_in[5];
    const float* wq     = (const float*)d_in[6];
    const float* wk     = (const float*)d_in[7];
    const float* wv     = (const float*)d_in[8];
    const float* wo     = (const float*)d_in[9];
    const float* bq     = (const float*)d_in[10];
    const float* bk     = (const float*)d_in[11];
    const float* bv     = (const float*)d_in[12];
    const float* bo     = (const float*)d_in[13];
    const float* ffn_w1 = (const float*)d_in[14];
    const float* ffn_b1 = (const float*)d_in[15];
    const float* ffn_w2 = (const float*)d_in[16];
    const float* ffn_b2 = (const float*)d_in[17];
    const float* pw_w   = (const float*)d_in[18];
    const float* pw_b   = (const float*)d_in[19];

    float* X            = (float*)d_ws;
    unsigned short* Hb  = (unsigned short*)(X + BUF);
    unsigned short* Qb  = Hb + BUF;
    unsigned short* Kb  = Qb + BUF;                  // K_t d-major
    unsigned short* Vb  = Kb + BUF;                  // V_t d-major
    unsigned short* hid = Vb + BUF;
    unsigned short* Eg  = hid + 2 * BUF;
    unsigned short* wqkvb = Eg + (size_t)NP * 64;
    const int QKVSZ = NBLK * 2 * 576 * CCH;          // 1327104
    const int WSZ   = NBLK * 2 * CCH * CCH;          // 442368
    const int FSZ   = NBLK * 768 * CCH;              // 884736
    unsigned short* wob = wqkvb + QKVSZ;
    unsigned short* w1b = wob + WSZ;
    unsigned short* w2b = w1b + FSZ;
    unsigned short* pjb = w2b + FSZ;                 // 12288
    float* bqkvb = (float*)(pjb + 12288 + 32);       // 12*576 fp32
    float* Xt = (float*)hid;

    wqkv_concat<<<QKVSZ / 256, 256, 0, stream>>>(wq, wk, wv, wqkvb);
    bqkv_concat<<<27, 256, 0, stream>>>(bq, bk, bv, bqkvb);
    convert_kernel<<<(WSZ + 255) / 256, 256, 0, stream>>>(wo, wob, WSZ);
    convert_kernel<<<(FSZ + 255) / 256, 256, 0, stream>>>(ffn_w1, w1b, FSZ);
    convert_kernel<<<(FSZ + 255) / 256, 256, 0, stream>>>(ffn_w2, w2b, FSZ);
    convert_kernel<<<48, 256, 0, stream>>>(proj_w, pjb, 12288);

    gather_kernel<<<NP * 64 / 256, 256, 0, stream>>>(tokens, emb, Eg);
    mm_bf16<0, 2, 0, 0, 0><<<dim3(2, 256), 256, 0, stream>>>(Eg, pjb, proj_b, Xt,
                                                             nullptr, nullptr, nullptr, NP, CCH, 64);
    rotary_kernel<<<NP / 4, 256, 0, stream>>>(Xt, X);

    for (int i = 0; i < NBLK; ++i) {
        for (int att = 0; att < 2; ++att) {
            const float* g  = ln_g + (size_t)(i * 3 + att) * CCH;
            const float* bn = ln_b + (size_t)(i * 3 + att) * CCH;
            ln_kernel<<<NP / 4, 256, 0, stream>>>(X, Hb, g, bn);
            size_t wi = (size_t)(i * 2 + att);
            const unsigned short* wqkvi = wqkvb + wi * 576 * CCH;
            const float* bqkvi = bqkvb + wi * 576;
            const unsigned short* woi = wob + wi * CCH * CCH;
            const float* boi = bo + wi * CCH;
            if (att == 0) {
                mm_bf16<0, 0, 0, 0, 1><<<dim3(6, 256), 256, 0, stream>>>(Hb, wqkvi, bqkvi, nullptr,
                                                                         Qb, Kb, Vb, NP, 576, CCH);
                attn_mfma<LL><<<BB * SS * NH / 4, 256, 0, stream>>>(Qb, Kb, Vb, Hb);
                mm_bf16<0, 1, 0, 1, 0><<<dim3(2, 256), 256, 0, stream>>>(Hb, woi, boi, X,
                                                                         nullptr, nullptr, nullptr, NP, CCH, CCH);
            } else {
                mm_bf16<0, 0, 0, 0, 2><<<dim3(6, 256), 256, 0, stream>>>(Hb, wqkvi, bqkvi, nullptr,
                                                                         Qb, Kb, Vb, NP, 576, CCH);
                attn_mfma<SS><<<BB * LL * NH / 4, 256, 0, stream>>>(Qb, Kb, Vb, Hb);
                mm_bf16<0, 1, 0, 2, 0><<<dim3(2, 256), 256, 0, stream>>>(Hb, woi, boi, X,
                                                                         nullptr, nullptr, nullptr, NP, CCH, CCH);
            }
        }
        const float* g  = ln_g + (size_t)(i * 3 + 2) * CCH;
        const float* bn = ln_b + (size_t)(i * 3 + 2) * CCH;
        ln_kernel<<<NP / 4, 256, 0, stream>>>(X, Hb, g, bn);
        const unsigned short* w1 = w1b + (size_t)i * 768 * CCH;
        const unsigned short* w2 = w2b + (size_t)i * CCH * 768;
        const float* b1 = ffn_b1 + (size_t)i * 768;
        const float* b2 = ffn_b2 + (size_t)i * CCH;
        for (int half = 0; half < 2; ++half) {
            size_t m0 = (size_t)half * (NP / 2);
            mm_bf16<3, 0, 0, 0, 0><<<dim3(8, 128), 256, 0, stream>>>(Hb + m0 * CCH, w1, b1, hid,
                                                                     nullptr, nullptr, nullptr, NP / 2, 768, CCH);
            mm_bf16<0, 1, 0, 0, 0><<<dim3(2, 128), 256, 0, stream>>>(hid, w2, b2, X + m0 * CCH,
                                                                     nullptr, nullptr, nullptr, NP / 2, CCH, 768);
        }
    }
    final_kernel<<<NP / 4, 256, 0, stream>>>(X, pw_w, pw_b, (float*)d_out);
}

// Round 5
// 1754.402 us; speedup vs baseline: 13.3012x; 1.2226x over previous
//
#include <hip/hip_runtime.h>
#include <hip/hip_bf16.h>
#include <math.h>

#define NBLK 6
#define NH 4
#define CCH 192
#define BB 2
#define SS 64
#define LL 256
#define DH 48
#define NP (BB*SS*LL)            // 32768 pixels
#define BUF ((size_t)NP*CCH)

typedef __attribute__((ext_vector_type(8))) short short8;
typedef __attribute__((ext_vector_type(4))) float float4v;

__device__ __forceinline__ unsigned short f2b(float f) {
    union { float f; unsigned int u; } v; v.f = f;
    unsigned int r = v.u + 0x7FFF + ((v.u >> 16) & 1);
    return (unsigned short)(r >> 16);
}
__device__ __forceinline__ float b2f(unsigned short u) {
    union { unsigned int u; float f; } v; v.u = ((unsigned int)u) << 16;
    return v.f;
}
__device__ __forceinline__ void async_lds16(const void* g, void* l) {
    __builtin_amdgcn_global_load_lds(
        (const __attribute__((address_space(1))) unsigned int*)g,
        (__attribute__((address_space(3))) unsigned int*)l, 16, 0, 0);
}

__global__ void convert_kernel(const float* __restrict__ s, unsigned short* __restrict__ d, int n) {
    int i = blockIdx.x * 256 + threadIdx.x;
    if (i < n) d[i] = f2b(s[i]);
}
__global__ void wqkv_concat(const float* __restrict__ wq, const float* __restrict__ wk,
                            const float* __restrict__ wv, unsigned short* __restrict__ d) {
    int idx = blockIdx.x * 256 + threadIdx.x;        // 12*576*192
    int wi = idx / (576 * CCH);
    int rem = idx - wi * 576 * CCH;
    int n = rem / CCH, k = rem - (rem / CCH) * CCH;
    int sg = n / 192, row = n - sg * 192;
    const float* src = (sg == 0) ? wq : (sg == 1) ? wk : wv;
    d[idx] = f2b(src[(size_t)wi * CCH * CCH + row * CCH + k]);
}
__global__ void bqkv_concat(const float* __restrict__ bq, const float* __restrict__ bk,
                            const float* __restrict__ bv, float* __restrict__ d) {
    int idx = blockIdx.x * 256 + threadIdx.x;        // 12*576
    if (idx >= NBLK * 2 * 576) return;
    int wi = idx / 576, n = idx - (idx / 576) * 576;
    int sg = n / 192, row = n - sg * 192;
    const float* src = (sg == 0) ? bq : (sg == 1) ? bk : bv;
    d[idx] = src[wi * CCH + row];
}

__global__ void gather_kernel(const int* __restrict__ tokens, const float* __restrict__ emb,
                              unsigned short* __restrict__ Eg) {
    int idx = blockIdx.x * 256 + threadIdx.x;   // NP*64
    int p = idx >> 6, c = idx & 63;
    Eg[idx] = f2b(emb[tokens[p] * 64 + c]);
}

__global__ __launch_bounds__(256) void rotary_kernel(const float* __restrict__ Xt, float* __restrict__ X) {
    int wave = threadIdx.x >> 6;
    int lane = threadIdx.x & 63;
    int p = blockIdx.x * 4 + wave;
    int l = p & (LL - 1);
    const float* xp = Xt + (size_t)p * CCH;
    float* op = X + (size_t)p * CCH;
    #pragma unroll
    for (int i = 0; i < 3; ++i) {
        int c = lane + i * 64;
        int j = c % 96;
        float inv = expf((float)(2 * j) * (-9.210340371976184f / 192.0f));
        float ang = (float)l * inv;
        float part = (c < 96) ? -xp[c + 96] : xp[c - 96];
        op[c] = xp[c] * cosf(ang) + part * sinf(ang);
    }
}

__global__ __launch_bounds__(256) void ln_kernel(const float* __restrict__ X, unsigned short* __restrict__ Hn,
                                                 const float* __restrict__ g, const float* __restrict__ b) {
    int wave = threadIdx.x >> 6;
    int lane = threadIdx.x & 63;
    int p = blockIdx.x * 4 + wave;
    const float* xp = X + (size_t)p * CCH;
    float v0 = xp[lane], v1 = xp[lane + 64], v2 = xp[lane + 128];
    float s = v0 + v1 + v2;
    float q = v0 * v0 + v1 * v1 + v2 * v2;
    #pragma unroll
    for (int off = 32; off; off >>= 1) {
        s += __shfl_xor(s, off, 64);
        q += __shfl_xor(q, off, 64);
    }
    float mean = s * (1.0f / 192.0f);
    float var = q * (1.0f / 192.0f) - mean * mean;
    float r = rsqrtf(var + 1e-5f);
    unsigned short* hp = Hn + (size_t)p * CCH;
    hp[lane]       = f2b((v0 - mean) * r * g[lane]       + b[lane]);
    hp[lane + 64]  = f2b((v1 - mean) * r * g[lane + 64]  + b[lane + 64]);
    hp[lane + 128] = f2b((v2 - mean) * r * g[lane + 128] + b[lane + 128]);
}

// ---------------- bf16 MFMA GEMM, plain layouts ----------------
// Tile 128x96, BK=64. ACT: 0 none, 3 exact gelu, 4 QKV-segmented (n<192: (elu+1)/sqrt48;
// n<384: elu+1; else none). OUT: 0 bf16 store, 1 fp32 +=, 2 fp32 store.
template<int ACT, int OUT>
__global__ __launch_bounds__(256, 2) void mm_bf16(const unsigned short* __restrict__ A,
                                                  const unsigned short* __restrict__ W,
                                                  const float* __restrict__ bias,
                                                  void* __restrict__ OutV,
                                                  int M, int N, int K) {
    unsigned short* Ob = (unsigned short*)OutV;
    float* Of = (float*)OutV;
    __shared__ __align__(16) unsigned char lds[28672];
    const int tid = threadIdx.x;
    const int lane = tid & 63;
    const int w = tid >> 6;
    const int wm = w >> 1, wn = w & 1;
    const int m0 = blockIdx.y * 128;
    const int n0 = blockIdx.x * 96;
    const int q8 = (lane >> 4) << 3;
    const int r15 = lane & 15;

    float4v acc[4][3];
    #pragma unroll
    for (int i = 0; i < 4; ++i)
        #pragma unroll
        for (int j = 0; j < 3; ++j)
            acc[i][j] = (float4v){0.f, 0.f, 0.f, 0.f};

    for (int k0 = 0; k0 < K; k0 += 64) {
        #pragma unroll
        for (int it = 0; it < 7; ++it) {
            int c = it * 4 + w;
            const unsigned short* gp;
            if (c < 16) {
                int g = c >> 1, s = c & 1;
                gp = A + (size_t)(m0 + g * 16 + r15) * K + k0 + s * 32 + q8;
            } else {
                int wc = c - 16;
                int g = wc >> 1, s = wc & 1;
                gp = W + (size_t)(n0 + g * 16 + r15) * K + k0 + s * 32 + q8;
            }
            async_lds16(gp, lds + c * 1024);
        }
        __syncthreads();
        #pragma unroll
        for (int s = 0; s < 2; ++s) {
            short8 af[4], wf[3];
            #pragma unroll
            for (int i = 0; i < 4; ++i)
                af[i] = *(const short8*)(lds + (((wm * 4 + i) * 2 + s) << 10) + lane * 16);
            #pragma unroll
            for (int j = 0; j < 3; ++j)
                wf[j] = *(const short8*)(lds + 16384 + (((wn * 3 + j) * 2 + s) << 10) + lane * 16);
            #pragma unroll
            for (int i = 0; i < 4; ++i)
                #pragma unroll
                for (int j = 0; j < 3; ++j)
                    acc[i][j] = __builtin_amdgcn_mfma_f32_16x16x32_bf16(af[i], wf[j], acc[i][j], 0, 0, 0);
        }
        __syncthreads();
    }

    const int nb = n0 + wn * 48 + r15;
    const int mb = m0 + wm * 64 + ((lane >> 4) << 2);
    #pragma unroll
    for (int j = 0; j < 3; ++j) {
        int n = nb + j * 16;
        float bv = bias[n];
        #pragma unroll
        for (int i = 0; i < 4; ++i) {
            int mrow = mb + i * 16;
            #pragma unroll
            for (int r = 0; r < 4; ++r) {
                float v = acc[i][j][r] + bv;
                if (ACT == 3) v = 0.5f * v * (1.0f + erff(v * 0.7071067811865475f));
                if (ACT == 4) {
                    if (n < 384) v = (v > 0.f) ? v + 1.f : expf(v);
                    if (n < 192) v *= 0.14433756729740643f;
                }
                int m = mrow + r;
                if (OUT == 1)      Of[(size_t)m * N + n] += v;
                else if (OUT == 2) Of[(size_t)m * N + n] = v;
                else               Ob[(size_t)m * N + n] = f2b(v);
            }
        }
    }
}

// ---------------- axial linear attention, plain [m][576] input, [m][192] output ----------------
// Block = 4 waves = 4 heads; one block per sequence-group.
// Row mode: MSTR=1, N=256, grid = BB*SS (base = blk*256).
// Col mode: MSTR=256, N=64, grid = BB*LL (base = (g>>8)*16384 + (g&255)).
// QKV cols: [0,192) Q (feature-mapped+scaled), [192,384) K (feature-mapped), [384,576) V.
template<int N, int MSTR>
__global__ __launch_bounds__(256) void attn_axial(const unsigned short* __restrict__ QKV,
                                                  unsigned short* __restrict__ O) {
    __shared__ unsigned short KV[32][400];        // staged rows: cols 0..191 K, 192..383 V
    __shared__ unsigned short kvs[4][64][72];     // per-wave: rows e, cols d; row48=ksum, rest 0
    const int tid = threadIdx.x;
    const int lane = tid & 63;
    const int w = tid >> 6;                       // head
    const int q = lane >> 4, r15 = lane & 15, q8 = q * 8;
    size_t base;
    if (MSTR == 1) base = (size_t)blockIdx.x * N;
    else           base = (size_t)(blockIdx.x >> 8) * 16384 + (blockIdx.x & 255);

    // zero this wave's kvs (4608 shorts = 2304 dwords)
    unsigned int* kz = (unsigned int*)&kvs[w][0][0];
    #pragma unroll
    for (int ii = 0; ii < 36; ++ii) kz[lane + ii * 64] = 0;

    short8 onesf;
    #pragma unroll
    for (int e = 0; e < 8; ++e) onesf[e] = (short)0x3F80;

    float4v kv[3][4];
    #pragma unroll
    for (int i = 0; i < 3; ++i)
        #pragma unroll
        for (int j = 0; j < 4; ++j)
            kv[i][j] = (float4v){0.f, 0.f, 0.f, 0.f};

    // pass 1: kv[d][e] = sum_n K[n][d] V[n][e]; kv[i][3] accumulates ksum (ones trick)
    for (int ks = 0; ks < N; ks += 32) {
        #pragma unroll
        for (int it = 0; it < 6; ++it) {
            int cc = tid + it * 256;              // 1536 chunks of 8 shorts
            int row = cc / 48, c8 = cc - (cc / 48) * 48;
            const unsigned short* gp = QKV + ((size_t)(base + (size_t)(ks + row) * MSTR)) * 576 + 192 + c8 * 8;
            *(short8*)&KV[row][c8 * 8] = *(const short8*)gp;
        }
        __syncthreads();
        short8 af[3], bf[3];
        #pragma unroll
        for (int t = 0; t < 3; ++t) {
            #pragma unroll
            for (int j = 0; j < 8; ++j) {
                af[t][j] = (short)KV[q8 + j][w * 48 + t * 16 + r15];
                bf[t][j] = (short)KV[q8 + j][192 + w * 48 + t * 16 + r15];
            }
        }
        #pragma unroll
        for (int i = 0; i < 3; ++i) {
            #pragma unroll
            for (int j = 0; j < 3; ++j)
                kv[i][j] = __builtin_amdgcn_mfma_f32_16x16x32_bf16(af[i], bf[j], kv[i][j], 0, 0, 0);
            kv[i][3] = __builtin_amdgcn_mfma_f32_16x16x32_bf16(af[i], onesf, kv[i][3], 0, 0, 0);
        }
        __syncthreads();
    }

    // kv -> kvs bf16 (wave-private, no barrier): row e = j*16+r15, col d = i*16+q*4+r
    #pragma unroll
    for (int i = 0; i < 3; ++i) {
        #pragma unroll
        for (int j = 0; j < 3; ++j)
            #pragma unroll
            for (int r = 0; r < 4; ++r)
                kvs[w][j * 16 + r15][i * 16 + q * 4 + r] = f2b(kv[i][j][r]);
        if (r15 == 0)
            #pragma unroll
            for (int r = 0; r < 4; ++r)
                kvs[w][48][i * 16 + q * 4 + r] = f2b(kv[i][3][r]);
    }

    // pass 2: O[n][e] = (Q[n][:] @ kv) * z, denom via kvs row 48
    short8 bkv[2][4];
    #pragma unroll
    for (int kk = 0; kk < 2; ++kk)
        #pragma unroll
        for (int t = 0; t < 4; ++t)
            bkv[kk][t] = *(const short8*)&kvs[w][t * 16 + r15][kk * 32 + q8];

    for (int mt = 0; mt < N / 16; ++mt) {
        float4v o[4];
        #pragma unroll
        for (int t = 0; t < 4; ++t) o[t] = (float4v){0.f, 0.f, 0.f, 0.f};
        #pragma unroll
        for (int kk = 0; kk < 2; ++kk) {
            const unsigned short* qp = QKV + ((size_t)(base + (size_t)(mt * 16 + r15) * MSTR)) * 576
                                       + w * 48 + kk * 32 + q8;
            short8 aq = *(const short8*)qp;
            #pragma unroll
            for (int t = 0; t < 4; ++t)
                o[t] = __builtin_amdgcn_mfma_f32_16x16x32_bf16(aq, bkv[kk][t], o[t], 0, 0, 0);
        }
        #pragma unroll
        for (int r = 0; r < 4; ++r) {
            float den = __shfl(o[3][r], q << 4);
            float z = 1.0f / (den + 1e-6f);
            int n = mt * 16 + q * 4 + r;
            unsigned short* op = O + ((size_t)(base + (size_t)n * MSTR)) * 192 + w * 48;
            #pragma unroll
            for (int t = 0; t < 3; ++t)
                op[t * 16 + r15] = f2b(o[t][r] * z);
        }
    }
}

__global__ __launch_bounds__(256) void final_kernel(const float* __restrict__ X, const float* __restrict__ pw_w,
                                                    const float* __restrict__ pw_b, float* __restrict__ out) {
    int wave = threadIdx.x >> 6;
    int lane = threadIdx.x & 63;
    int p = blockIdx.x * 4 + wave;
    const float* xp = X + (size_t)p * CCH;
    float s = xp[lane] * pw_w[lane] + xp[lane + 64] * pw_w[lane + 64] + xp[lane + 128] * pw_w[lane + 128];
    #pragma unroll
    for (int off = 32; off; off >>= 1) s += __shfl_xor(s, off, 64);
    if (lane == 0) {
        float o = s + pw_b[0];
        float e = expf(o);
        out[p] = 1.0f - 1.0f / (2.0f + e);
    }
}

extern "C" void kernel_launch(void* const* d_in, const int* in_sizes, int n_in,
                              void* d_out, int out_size, void* d_ws, size_t ws_size,
                              hipStream_t stream) {
    const int*   tokens = (const int*)  d_in[0];
    const float* emb    = (const float*)d_in[1];
    const float* proj_w = (const float*)d_in[2];
    const float* proj_b = (const float*)d_in[3];
    const float* ln_g   = (const float*)d_in[4];
    const float* ln_b   = (const float*)d_in[5];
    const float* wq     = (const float*)d_in[6];
    const float* wk     = (const float*)d_in[7];
    const float* wv     = (const float*)d_in[8];
    const float* wo     = (const float*)d_in[9];
    const float* bq     = (const float*)d_in[10];
    const float* bk     = (const float*)d_in[11];
    const float* bv     = (const float*)d_in[12];
    const float* bo     = (const float*)d_in[13];
    const float* ffn_w1 = (const float*)d_in[14];
    const float* ffn_b1 = (const float*)d_in[15];
    const float* ffn_w2 = (const float*)d_in[16];
    const float* ffn_b2 = (const float*)d_in[17];
    const float* pw_w   = (const float*)d_in[18];
    const float* pw_b   = (const float*)d_in[19];

    float* X             = (float*)d_ws;
    unsigned short* Hb   = (unsigned short*)(X + BUF);   // LN out / attn out
    unsigned short* QKVb = Hb + BUF;                     // NP x 576
    unsigned short* hid  = QKVb + 3 * BUF;               // 2*BUF
    unsigned short* Eg   = hid + 2 * BUF;                // NP*64
    unsigned short* wqkvb = Eg + (size_t)NP * 64;
    const int QKVSZ = NBLK * 2 * 576 * CCH;              // 1327104
    const int WSZ   = NBLK * 2 * CCH * CCH;              // 442368
    const int FSZ   = NBLK * 768 * CCH;                  // 884736
    unsigned short* wob = wqkvb + QKVSZ;
    unsigned short* w1b = wob + WSZ;
    unsigned short* w2b = w1b + FSZ;
    unsigned short* pjb = w2b + FSZ;                     // 12288
    float* bqkvb = (float*)(pjb + 12288 + 32);           // 12*576 fp32
    float* Xt = (float*)hid;

    wqkv_concat<<<QKVSZ / 256, 256, 0, stream>>>(wq, wk, wv, wqkvb);
    bqkv_concat<<<27, 256, 0, stream>>>(bq, bk, bv, bqkvb);
    convert_kernel<<<(WSZ + 255) / 256, 256, 0, stream>>>(wo, wob, WSZ);
    convert_kernel<<<(FSZ + 255) / 256, 256, 0, stream>>>(ffn_w1, w1b, FSZ);
    convert_kernel<<<(FSZ + 255) / 256, 256, 0, stream>>>(ffn_w2, w2b, FSZ);
    convert_kernel<<<48, 256, 0, stream>>>(proj_w, pjb, 12288);

    gather_kernel<<<NP * 64 / 256, 256, 0, stream>>>(tokens, emb, Eg);
    mm_bf16<0, 2><<<dim3(2, 256), 256, 0, stream>>>(Eg, pjb, proj_b, Xt, NP, CCH, 64);
    rotary_kernel<<<NP / 4, 256, 0, stream>>>(Xt, X);

    for (int i = 0; i < NBLK; ++i) {
        for (int att = 0; att < 2; ++att) {
            const float* g  = ln_g + (size_t)(i * 3 + att) * CCH;
            const float* bn = ln_b + (size_t)(i * 3 + att) * CCH;
            ln_kernel<<<NP / 4, 256, 0, stream>>>(X, Hb, g, bn);
            size_t wi = (size_t)(i * 2 + att);
            const unsigned short* wqkvi = wqkvb + wi * 576 * CCH;
            const float* bqkvi = bqkvb + wi * 576;
            const unsigned short* woi = wob + wi * CCH * CCH;
            const float* boi = bo + wi * CCH;
            mm_bf16<4, 0><<<dim3(6, 256), 256, 0, stream>>>(Hb, wqkvi, bqkvi, QKVb, NP, 576, CCH);
            if (att == 0) attn_axial<LL, 1><<<BB * SS, 256, 0, stream>>>(QKVb, Hb);
            else          attn_axial<SS, LL><<<BB * LL, 256, 0, stream>>>(QKVb, Hb);
            mm_bf16<0, 1><<<dim3(2, 256), 256, 0, stream>>>(Hb, woi, boi, X, NP, CCH, CCH);
        }
        const float* g  = ln_g + (size_t)(i * 3 + 2) * CCH;
        const float* bn = ln_b + (size_t)(i * 3 + 2) * CCH;
        ln_kernel<<<NP / 4, 256, 0, stream>>>(X, Hb, g, bn);
        const unsigned short* w1 = w1b + (size_t)i * 768 * CCH;
        const unsigned short* w2 = w2b + (size_t)i * CCH * 768;
        const float* b1 = ffn_b1 + (size_t)i * 768;
        const float* b2 = ffn_b2 + (size_t)i * CCH;
        for (int half = 0; half < 2; ++half) {
            size_t m0 = (size_t)half * (NP / 2);
            mm_bf16<3, 0><<<dim3(8, 128), 256, 0, stream>>>(Hb + m0 * CCH, w1, b1, hid, NP / 2, 768, CCH);
            mm_bf16<0, 1><<<dim3(2, 128), 256, 0, stream>>>(hid, w2, b2, X + m0 * CCH, NP / 2, CCH, 768);
        }
    }
    final_kernel<<<NP / 4, 256, 0, stream>>>(X, pw_w, pw_b, (float*)d_out);
}

// Round 6
// 1439.976 us; speedup vs baseline: 16.2056x; 1.2184x over previous
//
#include <hip/hip_runtime.h>
#include <hip/hip_bf16.h>
#include <math.h>

#define NBLK 6
#define NH 4
#define CCH 192
#define BB 2
#define SS 64
#define LL 256
#define DH 48
#define NP (BB*SS*LL)            // 32768 pixels
#define BUF ((size_t)NP*CCH)

typedef __attribute__((ext_vector_type(8))) short short8;
typedef __attribute__((ext_vector_type(4))) float float4v;

__device__ __forceinline__ unsigned short f2b(float f) {
    union { float f; unsigned int u; } v; v.f = f;
    unsigned int r = v.u + 0x7FFF + ((v.u >> 16) & 1);
    return (unsigned short)(r >> 16);
}
__device__ __forceinline__ float b2f(unsigned short u) {
    union { unsigned int u; float f; } v; v.u = ((unsigned int)u) << 16;
    return v.f;
}
__device__ __forceinline__ void async_lds16(const void* g, void* l) {
    __builtin_amdgcn_global_load_lds(
        (const __attribute__((address_space(1))) unsigned int*)g,
        (__attribute__((address_space(3))) unsigned int*)l, 16, 0, 0);
}

__global__ void convert_kernel(const float* __restrict__ s, unsigned short* __restrict__ d, int n) {
    int i = blockIdx.x * 256 + threadIdx.x;
    if (i < n) d[i] = f2b(s[i]);
}
__global__ void wqkv_concat(const float* __restrict__ wq, const float* __restrict__ wk,
                            const float* __restrict__ wv, unsigned short* __restrict__ d) {
    int idx = blockIdx.x * 256 + threadIdx.x;        // 12*576*192
    int wi = idx / (576 * CCH);
    int rem = idx - wi * 576 * CCH;
    int n = rem / CCH, k = rem - (rem / CCH) * CCH;
    int sg = n / 192, row = n - sg * 192;
    const float* src = (sg == 0) ? wq : (sg == 1) ? wk : wv;
    d[idx] = f2b(src[(size_t)wi * CCH * CCH + row * CCH + k]);
}
__global__ void bqkv_concat(const float* __restrict__ bq, const float* __restrict__ bk,
                            const float* __restrict__ bv, float* __restrict__ d) {
    int idx = blockIdx.x * 256 + threadIdx.x;        // 12*576
    if (idx >= NBLK * 2 * 576) return;
    int wi = idx / 576, n = idx - (idx / 576) * 576;
    int sg = n / 192, row = n - sg * 192;
    const float* src = (sg == 0) ? bq : (sg == 1) ? bk : bv;
    d[idx] = src[wi * CCH + row];
}

__global__ void gather_kernel(const int* __restrict__ tokens, const float* __restrict__ emb,
                              unsigned short* __restrict__ Eg) {
    int idx = blockIdx.x * 256 + threadIdx.x;   // NP*64
    int p = idx >> 6, c = idx & 63;
    Eg[idx] = f2b(emb[tokens[p] * 64 + c]);
}

// rotary + first LayerNorm fused: X = rotary(Xt); Hb = LN(X; g, b)
__global__ __launch_bounds__(256) void rotary_ln_kernel(const float* __restrict__ Xt, float* __restrict__ X,
                                                        unsigned short* __restrict__ Hn,
                                                        const float* __restrict__ g, const float* __restrict__ b) {
    int wave = threadIdx.x >> 6;
    int lane = threadIdx.x & 63;
    int p = blockIdx.x * 4 + wave;
    int l = p & (LL - 1);
    const float* xp = Xt + (size_t)p * CCH;
    float v[3];
    #pragma unroll
    for (int i = 0; i < 3; ++i) {
        int c = lane + i * 64;
        int j = c % 96;
        float inv = expf((float)(2 * j) * (-9.210340371976184f / 192.0f));
        float ang = (float)l * inv;
        float part = (c < 96) ? -xp[c + 96] : xp[c - 96];
        v[i] = xp[c] * cosf(ang) + part * sinf(ang);
    }
    float s = v[0] + v[1] + v[2];
    float qq = v[0] * v[0] + v[1] * v[1] + v[2] * v[2];
    #pragma unroll
    for (int off = 32; off; off >>= 1) {
        s += __shfl_xor(s, off, 64);
        qq += __shfl_xor(qq, off, 64);
    }
    float mean = s * (1.0f / 192.0f);
    float var = qq * (1.0f / 192.0f) - mean * mean;
    float r = rsqrtf(var + 1e-5f);
    float* op = X + (size_t)p * CCH;
    unsigned short* hp = Hn + (size_t)p * CCH;
    #pragma unroll
    for (int i = 0; i < 3; ++i) {
        int c = lane + i * 64;
        op[c] = v[i];
        hp[c] = f2b((v[i] - mean) * r * g[c] + b[c]);
    }
}

// ---------------- bf16 MFMA GEMM, tile MT x 192, BK=64 ----------------
// 4 waves: wave (wm = w>>1, wn = w&1) covers (MT/2) rows x 96 cols = NI x 6 frags.
// ACT: 0 none, 3 exact gelu, 4 QKV-segmented (n<192: (elu+1)/sqrt48; n<384: elu+1).
// EPI: 0 bf16 store -> Ob ; 1 fp32 store -> Of ;
//      2 fused residual+LN (requires N=192): X += acc+bias, Hn = LN(X)*lng+lnb ;
//      3 fused residual only (X += acc+bias).
template<int MT, int ACT, int EPI>
__global__ __launch_bounds__(256, (MT == 128) ? 2 : 3)
void mm192(const unsigned short* __restrict__ A, const unsigned short* __restrict__ W,
           const float* __restrict__ bias, unsigned short* __restrict__ Ob,
           float* __restrict__ Of, float* __restrict__ Xres, unsigned short* __restrict__ Hn,
           const float* __restrict__ lng, const float* __restrict__ lnb,
           int M, int N, int K) {
    constexpr int NI = MT / 32;        // m-frags per wave
    constexpr int ACH = MT / 8;        // A chunks (1KB each)
    constexpr int TCH = ACH + 24;      // total chunks
    __shared__ __align__(16) unsigned char lds[TCH * 1024];
    const int tid = threadIdx.x;
    const int lane = tid & 63;
    const int w = tid >> 6;
    const int wm = w >> 1, wn = w & 1;
    const int m0 = blockIdx.y * MT;
    const int n0 = blockIdx.x * 192;
    const int q = lane >> 4;
    const int q8 = q << 3;
    const int r15 = lane & 15;

    float4v acc[NI][6];
    #pragma unroll
    for (int i = 0; i < NI; ++i)
        #pragma unroll
        for (int j = 0; j < 6; ++j)
            acc[i][j] = (float4v){0.f, 0.f, 0.f, 0.f};

    for (int k0 = 0; k0 < K; k0 += 64) {
        #pragma unroll
        for (int it = 0; it < TCH / 4; ++it) {
            int c = it * 4 + w;
            const unsigned short* gp;
            if (c < ACH) {
                int g = c >> 1, s = c & 1;
                gp = A + (size_t)(m0 + g * 16 + r15) * K + k0 + s * 32 + q8;
            } else {
                int wc = c - ACH;
                int g = wc >> 1, s = wc & 1;
                gp = W + (size_t)(n0 + g * 16 + r15) * K + k0 + s * 32 + q8;
            }
            async_lds16(gp, lds + c * 1024);
        }
        __syncthreads();
        #pragma unroll
        for (int s = 0; s < 2; ++s) {
            short8 af[NI], wf[6];
            #pragma unroll
            for (int i = 0; i < NI; ++i)
                af[i] = *(const short8*)(lds + (((wm * NI + i) * 2 + s) << 10) + lane * 16);
            #pragma unroll
            for (int j = 0; j < 6; ++j)
                wf[j] = *(const short8*)(lds + ((ACH + (wn * 6 + j) * 2 + s) << 10) + lane * 16);
            #pragma unroll
            for (int i = 0; i < NI; ++i)
                #pragma unroll
                for (int j = 0; j < 6; ++j)
                    acc[i][j] = __builtin_amdgcn_mfma_f32_16x16x32_bf16(af[i], wf[j], acc[i][j], 0, 0, 0);
        }
        __syncthreads();
    }

    const int nb = n0 + wn * 96 + r15;
    const int mb = m0 + wm * (MT / 2) + q * 4;

    if (EPI <= 1) {
        #pragma unroll
        for (int j = 0; j < 6; ++j) {
            int n = nb + j * 16;
            float bv = bias[n];
            #pragma unroll
            for (int i = 0; i < NI; ++i) {
                int mrow = mb + i * 16;
                #pragma unroll
                for (int r = 0; r < 4; ++r) {
                    float v = acc[i][j][r] + bv;
                    if (ACT == 3) v = 0.5f * v * (1.0f + erff(v * 0.7071067811865475f));
                    if (ACT == 4) {
                        if (n < 384) v = (v > 0.f) ? v + 1.f : expf(v);
                        if (n < 192) v *= 0.14433756729740643f;
                    }
                    int m = mrow + r;
                    if (EPI == 1) Of[(size_t)m * N + n] = v;
                    else          Ob[(size_t)m * N + n] = f2b(v);
                }
            }
        }
    } else {
        // residual(+LN) epilogue; N == 192, n0 == 0.
        #pragma unroll
        for (int j = 0; j < 6; ++j) {
            int n = nb + j * 16;
            float bv = bias[n];
            #pragma unroll
            for (int i = 0; i < NI; ++i) {
                int mrow = mb + i * 16;
                #pragma unroll
                for (int r = 0; r < 4; ++r)
                    acc[i][j][r] += bv + Xres[(size_t)(mrow + r) * 192 + n];
            }
        }
        float* lsum = (float*)lds;           // [MT][2]
        float* lsq  = lsum + 2 * MT;         // [MT][2]
        #pragma unroll
        for (int i = 0; i < NI; ++i)
            #pragma unroll
            for (int r = 0; r < 4; ++r) {
                float s1 = 0.f, s2 = 0.f;
                #pragma unroll
                for (int j = 0; j < 6; ++j) {
                    float v = acc[i][j][r];
                    s1 += v; s2 += v * v;
                }
                #pragma unroll
                for (int off = 1; off < 16; off <<= 1) {
                    s1 += __shfl_xor(s1, off, 64);
                    s2 += __shfl_xor(s2, off, 64);
                }
                if (r15 == 0) {
                    int rl = wm * (MT / 2) + i * 16 + q * 4 + r;
                    lsum[rl * 2 + wn] = s1;
                    lsq[rl * 2 + wn] = s2;
                }
            }
        __syncthreads();
        #pragma unroll
        for (int i = 0; i < NI; ++i)
            #pragma unroll
            for (int r = 0; r < 4; ++r) {
                int rl = wm * (MT / 2) + i * 16 + q * 4 + r;
                int m = m0 + rl;
                float mean = (lsum[rl * 2] + lsum[rl * 2 + 1]) * (1.0f / 192.0f);
                float var = (lsq[rl * 2] + lsq[rl * 2 + 1]) * (1.0f / 192.0f) - mean * mean;
                float rstd = rsqrtf(var + 1e-5f);
                #pragma unroll
                for (int j = 0; j < 6; ++j) {
                    int n = nb + j * 16;
                    float v = acc[i][j][r];
                    Xres[(size_t)m * 192 + n] = v;
                    if (EPI == 2)
                        Hn[(size_t)m * 192 + n] = f2b((v - mean) * rstd * lng[n] + lnb[n]);
                }
            }
    }
}

// ---------------- axial linear attention, plain [m][576] input, [m][192] output ----------------
template<int N, int MSTR>
__global__ __launch_bounds__(256) void attn_axial(const unsigned short* __restrict__ QKV,
                                                  unsigned short* __restrict__ O) {
    __shared__ unsigned short KV[32][400];
    __shared__ unsigned short kvs[4][64][72];
    const int tid = threadIdx.x;
    const int lane = tid & 63;
    const int w = tid >> 6;                       // head
    const int q = lane >> 4, r15 = lane & 15, q8 = q * 8;
    size_t base;
    if (MSTR == 1) base = (size_t)blockIdx.x * N;
    else           base = (size_t)(blockIdx.x >> 8) * 16384 + (blockIdx.x & 255);

    unsigned int* kz = (unsigned int*)&kvs[w][0][0];
    #pragma unroll
    for (int ii = 0; ii < 36; ++ii) kz[lane + ii * 64] = 0;

    short8 onesf;
    #pragma unroll
    for (int e = 0; e < 8; ++e) onesf[e] = (short)0x3F80;

    float4v kv[3][4];
    #pragma unroll
    for (int i = 0; i < 3; ++i)
        #pragma unroll
        for (int j = 0; j < 4; ++j)
            kv[i][j] = (float4v){0.f, 0.f, 0.f, 0.f};

    for (int ks = 0; ks < N; ks += 32) {
        #pragma unroll
        for (int it = 0; it < 6; ++it) {
            int cc = tid + it * 256;
            int row = cc / 48, c8 = cc - (cc / 48) * 48;
            const unsigned short* gp = QKV + ((size_t)(base + (size_t)(ks + row) * MSTR)) * 576 + 192 + c8 * 8;
            *(short8*)&KV[row][c8 * 8] = *(const short8*)gp;
        }
        __syncthreads();
        short8 af[3], bf[3];
        #pragma unroll
        for (int t = 0; t < 3; ++t) {
            #pragma unroll
            for (int j = 0; j < 8; ++j) {
                af[t][j] = (short)KV[q8 + j][w * 48 + t * 16 + r15];
                bf[t][j] = (short)KV[q8 + j][192 + w * 48 + t * 16 + r15];
            }
        }
        #pragma unroll
        for (int i = 0; i < 3; ++i) {
            #pragma unroll
            for (int j = 0; j < 3; ++j)
                kv[i][j] = __builtin_amdgcn_mfma_f32_16x16x32_bf16(af[i], bf[j], kv[i][j], 0, 0, 0);
            kv[i][3] = __builtin_amdgcn_mfma_f32_16x16x32_bf16(af[i], onesf, kv[i][3], 0, 0, 0);
        }
        __syncthreads();
    }

    #pragma unroll
    for (int i = 0; i < 3; ++i) {
        #pragma unroll
        for (int j = 0; j < 3; ++j)
            #pragma unroll
            for (int r = 0; r < 4; ++r)
                kvs[w][j * 16 + r15][i * 16 + q * 4 + r] = f2b(kv[i][j][r]);
        if (r15 == 0)
            #pragma unroll
            for (int r = 0; r < 4; ++r)
                kvs[w][48][i * 16 + q * 4 + r] = f2b(kv[i][3][r]);
    }

    short8 bkv[2][4];
    #pragma unroll
    for (int kk = 0; kk < 2; ++kk)
        #pragma unroll
        for (int t = 0; t < 4; ++t)
            bkv[kk][t] = *(const short8*)&kvs[w][t * 16 + r15][kk * 32 + q8];

    for (int mt = 0; mt < N / 16; ++mt) {
        float4v o[4];
        #pragma unroll
        for (int t = 0; t < 4; ++t) o[t] = (float4v){0.f, 0.f, 0.f, 0.f};
        #pragma unroll
        for (int kk = 0; kk < 2; ++kk) {
            const unsigned short* qp = QKV + ((size_t)(base + (size_t)(mt * 16 + r15) * MSTR)) * 576
                                       + w * 48 + kk * 32 + q8;
            short8 aq = *(const short8*)qp;
            #pragma unroll
            for (int t = 0; t < 4; ++t)
                o[t] = __builtin_amdgcn_mfma_f32_16x16x32_bf16(aq, bkv[kk][t], o[t], 0, 0, 0);
        }
        #pragma unroll
        for (int r = 0; r < 4; ++r) {
            float den = __shfl(o[3][r], q << 4);
            float z = 1.0f / (den + 1e-6f);
            int n = mt * 16 + q * 4 + r;
            unsigned short* op = O + ((size_t)(base + (size_t)n * MSTR)) * 192 + w * 48;
            #pragma unroll
            for (int t = 0; t < 3; ++t)
                op[t * 16 + r15] = f2b(o[t][r] * z);
        }
    }
}

__global__ __launch_bounds__(256) void final_kernel(const float* __restrict__ X, const float* __restrict__ pw_w,
                                                    const float* __restrict__ pw_b, float* __restrict__ out) {
    int wave = threadIdx.x >> 6;
    int lane = threadIdx.x & 63;
    int p = blockIdx.x * 4 + wave;
    const float* xp = X + (size_t)p * CCH;
    float s = xp[lane] * pw_w[lane] + xp[lane + 64] * pw_w[lane + 64] + xp[lane + 128] * pw_w[lane + 128];
    #pragma unroll
    for (int off = 32; off; off >>= 1) s += __shfl_xor(s, off, 64);
    if (lane == 0) {
        float o = s + pw_b[0];
        float e = expf(o);
        out[p] = 1.0f - 1.0f / (2.0f + e);
    }
}

extern "C" void kernel_launch(void* const* d_in, const int* in_sizes, int n_in,
                              void* d_out, int out_size, void* d_ws, size_t ws_size,
                              hipStream_t stream) {
    const int*   tokens = (const int*)  d_in[0];
    const float* emb    = (const float*)d_in[1];
    const float* proj_w = (const float*)d_in[2];
    const float* proj_b = (const float*)d_in[3];
    const float* ln_g   = (const float*)d_in[4];
    const float* ln_b   = (const float*)d_in[5];
    const float* wq     = (const float*)d_in[6];
    const float* wk     = (const float*)d_in[7];
    const float* wv     = (const float*)d_in[8];
    const float* wo     = (const float*)d_in[9];
    const float* bq     = (const float*)d_in[10];
    const float* bk     = (const float*)d_in[11];
    const float* bv     = (const float*)d_in[12];
    const float* bo     = (const float*)d_in[13];
    const float* ffn_w1 = (const float*)d_in[14];
    const float* ffn_b1 = (const float*)d_in[15];
    const float* ffn_w2 = (const float*)d_in[16];
    const float* ffn_b2 = (const float*)d_in[17];
    const float* pw_w   = (const float*)d_in[18];
    const float* pw_b   = (const float*)d_in[19];

    float* X             = (float*)d_ws;                 // fp32 residual
    unsigned short* Hb   = (unsigned short*)(X + BUF);   // current LN output
    unsigned short* Ho   = Hb + BUF;                     // attn output
    unsigned short* QKVb = Ho + BUF;                     // NP x 576
    unsigned short* hid  = QKVb + 3 * BUF;               // NP x 768
    unsigned short* Eg   = hid + 4 * BUF;                // NP x 64
    unsigned short* wqkvb = Eg + (size_t)NP * 64;
    const int QKVSZ = NBLK * 2 * 576 * CCH;              // 1327104
    const int WSZ   = NBLK * 2 * CCH * CCH;              // 442368
    const int FSZ   = NBLK * 768 * CCH;                  // 884736
    unsigned short* wob = wqkvb + QKVSZ;
    unsigned short* w1b = wob + WSZ;
    unsigned short* w2b = w1b + FSZ;
    unsigned short* pjb = w2b + FSZ;                     // 12288
    float* bqkvb = (float*)(pjb + 12288 + 32);           // 12*576 fp32
    float* Xt = (float*)hid;                             // proj output tmp (aliases hid)

    wqkv_concat<<<QKVSZ / 256, 256, 0, stream>>>(wq, wk, wv, wqkvb);
    bqkv_concat<<<27, 256, 0, stream>>>(bq, bk, bv, bqkvb);
    convert_kernel<<<(WSZ + 255) / 256, 256, 0, stream>>>(wo, wob, WSZ);
    convert_kernel<<<(FSZ + 255) / 256, 256, 0, stream>>>(ffn_w1, w1b, FSZ);
    convert_kernel<<<(FSZ + 255) / 256, 256, 0, stream>>>(ffn_w2, w2b, FSZ);
    convert_kernel<<<48, 256, 0, stream>>>(proj_w, pjb, 12288);

    gather_kernel<<<NP * 64 / 256, 256, 0, stream>>>(tokens, emb, Eg);
    mm192<64, 0, 1><<<dim3(1, NP / 64), 256, 0, stream>>>(Eg, pjb, proj_b, nullptr, Xt,
                                                          nullptr, nullptr, nullptr, nullptr, NP, CCH, 64);
    rotary_ln_kernel<<<NP / 4, 256, 0, stream>>>(Xt, X, Hb, ln_g, ln_b);

    for (int i = 0; i < NBLK; ++i) {
        for (int att = 0; att < 2; ++att) {
            size_t wi = (size_t)(i * 2 + att);
            const unsigned short* wqkvi = wqkvb + wi * 576 * CCH;
            const float* bqkvi = bqkvb + wi * 576;
            const unsigned short* woi = wob + wi * CCH * CCH;
            const float* boi = bo + wi * CCH;
            const float* gn  = ln_g + (size_t)(i * 3 + att + 1) * CCH;   // next LN params
            const float* bnn = ln_b + (size_t)(i * 3 + att + 1) * CCH;
            mm192<128, 4, 0><<<dim3(3, NP / 128), 256, 0, stream>>>(Hb, wqkvi, bqkvi, QKVb, nullptr,
                                                                    nullptr, nullptr, nullptr, nullptr, NP, 576, CCH);
            if (att == 0) attn_axial<LL, 1><<<BB * SS, 256, 0, stream>>>(QKVb, Ho);
            else          attn_axial<SS, LL><<<BB * LL, 256, 0, stream>>>(QKVb, Ho);
            mm192<64, 0, 2><<<dim3(1, NP / 64), 256, 0, stream>>>(Ho, woi, boi, nullptr, nullptr,
                                                                  X, Hb, gn, bnn, NP, CCH, CCH);
        }
        const unsigned short* w1 = w1b + (size_t)i * 768 * CCH;
        const unsigned short* w2 = w2b + (size_t)i * CCH * 768;
        const float* b1 = ffn_b1 + (size_t)i * 768;
        const float* b2 = ffn_b2 + (size_t)i * CCH;
        mm192<128, 3, 0><<<dim3(4, NP / 128), 256, 0, stream>>>(Hb, w1, b1, hid, nullptr,
                                                                nullptr, nullptr, nullptr, nullptr, NP, 768, CCH);
        if (i < NBLK - 1) {
            const float* gn  = ln_g + (size_t)((i + 1) * 3) * CCH;
            const float* bnn = ln_b + (size_t)((i + 1) * 3) * CCH;
            mm192<64, 0, 2><<<dim3(1, NP / 64), 256, 0, stream>>>(hid, w2, b2, nullptr, nullptr,
                                                                  X, Hb, gn, bnn, NP, CCH, 768);
        } else {
            mm192<64, 0, 3><<<dim3(1, NP / 64), 256, 0, stream>>>(hid, w2, b2, nullptr, nullptr,
                                                                  X, nullptr, nullptr, nullptr, NP, CCH, 768);
        }
    }
    final_kernel<<<NP / 4, 256, 0, stream>>>(X, pw_w, pw_b, (float*)d_out);
}

// Round 7
// 1352.570 us; speedup vs baseline: 17.2529x; 1.0646x over previous
//
#include <hip/hip_runtime.h>
#include <hip/hip_bf16.h>
#include <math.h>

#define NBLK 6
#define NH 4
#define CCH 192
#define BB 2
#define SS 64
#define LL 256
#define DH 48
#define NP (BB*SS*LL)            // 32768 pixels
#define BUF ((size_t)NP*CCH)

typedef __attribute__((ext_vector_type(8))) short short8;
typedef __attribute__((ext_vector_type(4))) float float4v;

__device__ __forceinline__ unsigned short f2b(float f) {
    union { float f; unsigned int u; } v; v.f = f;
    unsigned int r = v.u + 0x7FFF + ((v.u >> 16) & 1);
    return (unsigned short)(r >> 16);
}
__device__ __forceinline__ float b2f(unsigned short u) {
    union { unsigned int u; float f; } v; v.u = ((unsigned int)u) << 16;
    return v.f;
}
__device__ __forceinline__ void async_lds16(const void* g, void* l) {
    __builtin_amdgcn_global_load_lds(
        (const __attribute__((address_space(1))) unsigned int*)g,
        (__attribute__((address_space(3))) unsigned int*)l, 16, 0, 0);
}

__global__ void convert_kernel(const float* __restrict__ s, unsigned short* __restrict__ d, int n) {
    int i = blockIdx.x * 256 + threadIdx.x;
    if (i < n) d[i] = f2b(s[i]);
}
__global__ void wqkv_concat(const float* __restrict__ wq, const float* __restrict__ wk,
                            const float* __restrict__ wv, unsigned short* __restrict__ d) {
    int idx = blockIdx.x * 256 + threadIdx.x;        // 12*576*192
    int wi = idx / (576 * CCH);
    int rem = idx - wi * 576 * CCH;
    int n = rem / CCH, k = rem - (rem / CCH) * CCH;
    int sg = n / 192, row = n - sg * 192;
    const float* src = (sg == 0) ? wq : (sg == 1) ? wk : wv;
    d[idx] = f2b(src[(size_t)wi * CCH * CCH + row * CCH + k]);
}
__global__ void bqkv_concat(const float* __restrict__ bq, const float* __restrict__ bk,
                            const float* __restrict__ bv, float* __restrict__ d) {
    int idx = blockIdx.x * 256 + threadIdx.x;        // 12*576
    if (idx >= NBLK * 2 * 576) return;
    int wi = idx / 576, n = idx - (idx / 576) * 576;
    int sg = n / 192, row = n - sg * 192;
    const float* src = (sg == 0) ? bq : (sg == 1) ? bk : bv;
    d[idx] = src[wi * CCH + row];
}

__global__ void gather_kernel(const int* __restrict__ tokens, const float* __restrict__ emb,
                              unsigned short* __restrict__ Eg) {
    int idx = blockIdx.x * 256 + threadIdx.x;   // NP*64
    int p = idx >> 6, c = idx & 63;
    Eg[idx] = f2b(emb[tokens[p] * 64 + c]);
}

// rotary + first LayerNorm fused
__global__ __launch_bounds__(256) void rotary_ln_kernel(const float* __restrict__ Xt, float* __restrict__ X,
                                                        unsigned short* __restrict__ Hn,
                                                        const float* __restrict__ g, const float* __restrict__ b) {
    int wave = threadIdx.x >> 6;
    int lane = threadIdx.x & 63;
    int p = blockIdx.x * 4 + wave;
    int l = p & (LL - 1);
    const float* xp = Xt + (size_t)p * CCH;
    float v[3];
    #pragma unroll
    for (int i = 0; i < 3; ++i) {
        int c = lane + i * 64;
        int j = c % 96;
        float inv = expf((float)(2 * j) * (-9.210340371976184f / 192.0f));
        float ang = (float)l * inv;
        float part = (c < 96) ? -xp[c + 96] : xp[c - 96];
        v[i] = xp[c] * cosf(ang) + part * sinf(ang);
    }
    float s = v[0] + v[1] + v[2];
    float qq = v[0] * v[0] + v[1] * v[1] + v[2] * v[2];
    #pragma unroll
    for (int off = 32; off; off >>= 1) {
        s += __shfl_xor(s, off, 64);
        qq += __shfl_xor(qq, off, 64);
    }
    float mean = s * (1.0f / 192.0f);
    float var = qq * (1.0f / 192.0f) - mean * mean;
    float r = rsqrtf(var + 1e-5f);
    float* op = X + (size_t)p * CCH;
    unsigned short* hp = Hn + (size_t)p * CCH;
    #pragma unroll
    for (int i = 0; i < 3; ++i) {
        int c = lane + i * 64;
        op[c] = v[i];
        hp[c] = f2b((v[i] - mean) * r * g[c] + b[c]);
    }
}

// ---------------- bf16 MFMA GEMM, tile MT x 192, BK=64 ----------------
// ACT: 0 none, 4 QKV-segmented. EPI: 0 bf16 store; 1 fp32 store; 2 residual+LN; 3 residual only.
template<int MT, int ACT, int EPI>
__global__ __launch_bounds__(256, (MT == 128) ? 2 : 3)
void mm192(const unsigned short* __restrict__ A, const unsigned short* __restrict__ W,
           const float* __restrict__ bias, unsigned short* __restrict__ Ob,
           float* __restrict__ Of, float* __restrict__ Xres, unsigned short* __restrict__ Hn,
           const float* __restrict__ lng, const float* __restrict__ lnb,
           int M, int N, int K) {
    constexpr int NI = MT / 32;
    constexpr int ACH = MT / 8;
    constexpr int TCH = ACH + 24;
    __shared__ __align__(16) unsigned char lds[TCH * 1024];
    const int tid = threadIdx.x;
    const int lane = tid & 63;
    const int w = tid >> 6;
    const int wm = w >> 1, wn = w & 1;
    const int m0 = blockIdx.y * MT;
    const int n0 = blockIdx.x * 192;
    const int q = lane >> 4;
    const int q8 = q << 3;
    const int r15 = lane & 15;

    float4v acc[NI][6];
    #pragma unroll
    for (int i = 0; i < NI; ++i)
        #pragma unroll
        for (int j = 0; j < 6; ++j)
            acc[i][j] = (float4v){0.f, 0.f, 0.f, 0.f};

    for (int k0 = 0; k0 < K; k0 += 64) {
        #pragma unroll
        for (int it = 0; it < TCH / 4; ++it) {
            int c = it * 4 + w;
            const unsigned short* gp;
            if (c < ACH) {
                int g = c >> 1, s = c & 1;
                gp = A + (size_t)(m0 + g * 16 + r15) * K + k0 + s * 32 + q8;
            } else {
                int wc = c - ACH;
                int g = wc >> 1, s = wc & 1;
                gp = W + (size_t)(n0 + g * 16 + r15) * K + k0 + s * 32 + q8;
            }
            async_lds16(gp, lds + c * 1024);
        }
        __syncthreads();
        #pragma unroll
        for (int s = 0; s < 2; ++s) {
            short8 af[NI], wf[6];
            #pragma unroll
            for (int i = 0; i < NI; ++i)
                af[i] = *(const short8*)(lds + (((wm * NI + i) * 2 + s) << 10) + lane * 16);
            #pragma unroll
            for (int j = 0; j < 6; ++j)
                wf[j] = *(const short8*)(lds + ((ACH + (wn * 6 + j) * 2 + s) << 10) + lane * 16);
            #pragma unroll
            for (int i = 0; i < NI; ++i)
                #pragma unroll
                for (int j = 0; j < 6; ++j)
                    acc[i][j] = __builtin_amdgcn_mfma_f32_16x16x32_bf16(af[i], wf[j], acc[i][j], 0, 0, 0);
        }
        __syncthreads();
    }

    const int nb = n0 + wn * 96 + r15;
    const int mb = m0 + wm * (MT / 2) + q * 4;

    if (EPI <= 1) {
        #pragma unroll
        for (int j = 0; j < 6; ++j) {
            int n = nb + j * 16;
            float bv = bias[n];
            #pragma unroll
            for (int i = 0; i < NI; ++i) {
                int mrow = mb + i * 16;
                #pragma unroll
                for (int r = 0; r < 4; ++r) {
                    float v = acc[i][j][r] + bv;
                    if (ACT == 4) {
                        if (n < 384) v = (v > 0.f) ? v + 1.f : expf(v);
                        if (n < 192) v *= 0.14433756729740643f;
                    }
                    int m = mrow + r;
                    if (EPI == 1) Of[(size_t)m * N + n] = v;
                    else          Ob[(size_t)m * N + n] = f2b(v);
                }
            }
        }
    } else {
        #pragma unroll
        for (int j = 0; j < 6; ++j) {
            int n = nb + j * 16;
            float bv = bias[n];
            #pragma unroll
            for (int i = 0; i < NI; ++i) {
                int mrow = mb + i * 16;
                #pragma unroll
                for (int r = 0; r < 4; ++r)
                    acc[i][j][r] += bv + Xres[(size_t)(mrow + r) * 192 + n];
            }
        }
        float* lsum = (float*)lds;
        float* lsq  = lsum + 2 * MT;
        #pragma unroll
        for (int i = 0; i < NI; ++i)
            #pragma unroll
            for (int r = 0; r < 4; ++r) {
                float s1 = 0.f, s2 = 0.f;
                #pragma unroll
                for (int j = 0; j < 6; ++j) {
                    float v = acc[i][j][r];
                    s1 += v; s2 += v * v;
                }
                #pragma unroll
                for (int off = 1; off < 16; off <<= 1) {
                    s1 += __shfl_xor(s1, off, 64);
                    s2 += __shfl_xor(s2, off, 64);
                }
                if (r15 == 0) {
                    int rl = wm * (MT / 2) + i * 16 + q * 4 + r;
                    lsum[rl * 2 + wn] = s1;
                    lsq[rl * 2 + wn] = s2;
                }
            }
        __syncthreads();
        #pragma unroll
        for (int i = 0; i < NI; ++i)
            #pragma unroll
            for (int r = 0; r < 4; ++r) {
                int rl = wm * (MT / 2) + i * 16 + q * 4 + r;
                int m = m0 + rl;
                float mean = (lsum[rl * 2] + lsum[rl * 2 + 1]) * (1.0f / 192.0f);
                float var = (lsq[rl * 2] + lsq[rl * 2 + 1]) * (1.0f / 192.0f) - mean * mean;
                float rstd = rsqrtf(var + 1e-5f);
                #pragma unroll
                for (int j = 0; j < 6; ++j) {
                    int n = nb + j * 16;
                    float v = acc[i][j][r];
                    Xres[(size_t)m * 192 + n] = v;
                    if (EPI == 2)
                        Hn[(size_t)m * 192 + n] = f2b((v - mean) * rstd * lng[n] + lnb[n]);
                }
            }
    }
}

// ---------------- fused FFN: Hn/X = LN-epilogue( X + gelu(A@W1^T+b1)@W2^T + b2 ) ----------------
// 64 rows/block. LDS: A tile 24K | W stage 24K | hidT 24K. Hidden never hits global.
template<bool LASTB>
__global__ __launch_bounds__(256, 2)
void ffn_fused(const unsigned short* __restrict__ A,      // [NP][192] bf16 (LN output)
               const unsigned short* __restrict__ W1,     // [768][192]
               const float* __restrict__ B1,
               const unsigned short* __restrict__ W2,     // [192][768]
               const float* __restrict__ B2,
               float* __restrict__ Xres,
               unsigned short* __restrict__ Hn,
               const float* __restrict__ lng, const float* __restrict__ lnb) {
    __shared__ __align__(16) unsigned char lds[73728];
    unsigned char* Areg = lds;            // 24 chunks (g 0..3, sk 0..5)
    unsigned char* Wreg = lds + 24576;    // 24 chunks (gn 0..11, s 0..1)
    unsigned char* Hreg = lds + 49152;    // 24 chunks, same layout as Areg
    const int tid = threadIdx.x;
    const int lane = tid & 63;
    const int w = tid >> 6;
    const int wm = w >> 1, wn = w & 1;
    const int m0 = blockIdx.x * 64;
    const int q = lane >> 4, q8 = q << 3, r15 = lane & 15;

    // stage A tile 64x192 once
    #pragma unroll
    for (int it = 0; it < 6; ++it) {
        int c = it * 4 + w;
        int g = c / 6, sk = c - (c / 6) * 6;
        async_lds16(A + (size_t)(m0 + g * 16 + r15) * 192 + sk * 32 + q8, Areg + c * 1024);
    }

    float4v acc2[2][6];
    #pragma unroll
    for (int i = 0; i < 2; ++i)
        #pragma unroll
        for (int j = 0; j < 6; ++j)
            acc2[i][j] = (float4v){0.f, 0.f, 0.f, 0.f};

    for (int hc = 0; hc < 4; ++hc) {
        float4v acc1[2][6];
        #pragma unroll
        for (int i = 0; i < 2; ++i)
            #pragma unroll
            for (int j = 0; j < 6; ++j)
                acc1[i][j] = (float4v){0.f, 0.f, 0.f, 0.f};

        // GEMM1: acc1 = A @ W1[hc*192 .. +192)^T
        for (int ks = 0; ks < 3; ++ks) {
            #pragma unroll
            for (int it = 0; it < 6; ++it) {
                int c = it * 4 + w;
                int gn = c >> 1, s = c & 1;
                async_lds16(W1 + (size_t)(hc * 192 + gn * 16 + r15) * 192 + ks * 64 + s * 32 + q8,
                            Wreg + c * 1024);
            }
            __syncthreads();
            #pragma unroll
            for (int s = 0; s < 2; ++s) {
                short8 af[2], wf[6];
                #pragma unroll
                for (int i = 0; i < 2; ++i)
                    af[i] = *(const short8*)(Areg + (((wm * 2 + i) * 6 + ks * 2 + s) << 10) + lane * 16);
                #pragma unroll
                for (int j = 0; j < 6; ++j)
                    wf[j] = *(const short8*)(Wreg + ((((wn * 6 + j) * 2) + s) << 10) + lane * 16);
                #pragma unroll
                for (int i = 0; i < 2; ++i)
                    #pragma unroll
                    for (int j = 0; j < 6; ++j)
                        acc1[i][j] = __builtin_amdgcn_mfma_f32_16x16x32_bf16(af[i], wf[j], acc1[i][j], 0, 0, 0);
            }
            __syncthreads();
        }
        // gelu -> hidT (A-fragment layout)
        #pragma unroll
        for (int i = 0; i < 2; ++i) {
            int g = wm * 2 + i;
            #pragma unroll
            for (int j = 0; j < 6; ++j) {
                int h = wn * 96 + j * 16 + r15;
                float bv = B1[hc * 192 + h];
                int sk = h >> 5;
                int base = (g * 6 + sk) * 512 + ((h >> 3) & 3) * 128 + (h & 7);
                #pragma unroll
                for (int r = 0; r < 4; ++r) {
                    float v = acc1[i][j][r] + bv;
                    v = 0.5f * v * (1.0f + erff(v * 0.7071067811865475f));
                    ((unsigned short*)Hreg)[base + (q * 4 + r) * 8] = f2b(v);
                }
            }
        }
        // GEMM2: acc2 += hidT @ W2[:, hc*192 .. +192)^T
        for (int ks = 0; ks < 3; ++ks) {
            #pragma unroll
            for (int it = 0; it < 6; ++it) {
                int c = it * 4 + w;
                int gn = c >> 1, s = c & 1;
                async_lds16(W2 + (size_t)(gn * 16 + r15) * 768 + hc * 192 + ks * 64 + s * 32 + q8,
                            Wreg + c * 1024);
            }
            __syncthreads();
            #pragma unroll
            for (int s = 0; s < 2; ++s) {
                short8 af[2], wf[6];
                #pragma unroll
                for (int i = 0; i < 2; ++i)
                    af[i] = *(const short8*)(Hreg + (((wm * 2 + i) * 6 + ks * 2 + s) << 10) + lane * 16);
                #pragma unroll
                for (int j = 0; j < 6; ++j)
                    wf[j] = *(const short8*)(Wreg + ((((wn * 6 + j) * 2) + s) << 10) + lane * 16);
                #pragma unroll
                for (int i = 0; i < 2; ++i)
                    #pragma unroll
                    for (int j = 0; j < 6; ++j)
                        acc2[i][j] = __builtin_amdgcn_mfma_f32_16x16x32_bf16(af[i], wf[j], acc2[i][j], 0, 0, 0);
            }
            __syncthreads();
        }
    }

    // residual + LN epilogue
    const int nb = wn * 96 + r15;
    const int mb = m0 + wm * 32 + q * 4;
    #pragma unroll
    for (int j = 0; j < 6; ++j) {
        int n = nb + j * 16;
        float bv = B2[n];
        #pragma unroll
        for (int i = 0; i < 2; ++i) {
            int mrow = mb + i * 16;
            #pragma unroll
            for (int r = 0; r < 4; ++r)
                acc2[i][j][r] += bv + Xres[(size_t)(mrow + r) * 192 + n];
        }
    }
    float* lsum = (float*)lds;
    float* lsq  = lsum + 128;
    #pragma unroll
    for (int i = 0; i < 2; ++i)
        #pragma unroll
        for (int r = 0; r < 4; ++r) {
            float s1 = 0.f, s2 = 0.f;
            #pragma unroll
            for (int j = 0; j < 6; ++j) {
                float v = acc2[i][j][r];
                s1 += v; s2 += v * v;
            }
            #pragma unroll
            for (int off = 1; off < 16; off <<= 1) {
                s1 += __shfl_xor(s1, off, 64);
                s2 += __shfl_xor(s2, off, 64);
            }
            if (r15 == 0) {
                int rl = wm * 32 + i * 16 + q * 4 + r;
                lsum[rl * 2 + wn] = s1;
                lsq[rl * 2 + wn] = s2;
            }
        }
    __syncthreads();
    #pragma unroll
    for (int i = 0; i < 2; ++i)
        #pragma unroll
        for (int r = 0; r < 4; ++r) {
            int rl = wm * 32 + i * 16 + q * 4 + r;
            int m = m0 + rl;
            float mean = (lsum[rl * 2] + lsum[rl * 2 + 1]) * (1.0f / 192.0f);
            float var = (lsq[rl * 2] + lsq[rl * 2 + 1]) * (1.0f / 192.0f) - mean * mean;
            float rstd = rsqrtf(var + 1e-5f);
            #pragma unroll
            for (int j = 0; j < 6; ++j) {
                int n = nb + j * 16;
                float v = acc2[i][j][r];
                Xres[(size_t)m * 192 + n] = v;
                if (!LASTB)
                    Hn[(size_t)m * 192 + n] = f2b((v - mean) * rstd * lng[n] + lnb[n]);
            }
        }
}

// ---------------- axial linear attention ----------------
template<int N, int MSTR>
__global__ __launch_bounds__(256) void attn_axial(const unsigned short* __restrict__ QKV,
                                                  unsigned short* __restrict__ O) {
    __shared__ unsigned short KV[32][400];
    __shared__ unsigned short kvs[4][64][72];
    const int tid = threadIdx.x;
    const int lane = tid & 63;
    const int w = tid >> 6;
    const int q = lane >> 4, r15 = lane & 15, q8 = q * 8;
    size_t base;
    if (MSTR == 1) base = (size_t)blockIdx.x * N;
    else           base = (size_t)(blockIdx.x >> 8) * 16384 + (blockIdx.x & 255);

    unsigned int* kz = (unsigned int*)&kvs[w][0][0];
    #pragma unroll
    for (int ii = 0; ii < 36; ++ii) kz[lane + ii * 64] = 0;

    short8 onesf;
    #pragma unroll
    for (int e = 0; e < 8; ++e) onesf[e] = (short)0x3F80;

    float4v kv[3][4];
    #pragma unroll
    for (int i = 0; i < 3; ++i)
        #pragma unroll
        for (int j = 0; j < 4; ++j)
            kv[i][j] = (float4v){0.f, 0.f, 0.f, 0.f};

    for (int ks = 0; ks < N; ks += 32) {
        #pragma unroll
        for (int it = 0; it < 6; ++it) {
            int cc = tid + it * 256;
            int row = cc / 48, c8 = cc - (cc / 48) * 48;
            const unsigned short* gp = QKV + ((size_t)(base + (size_t)(ks + row) * MSTR)) * 576 + 192 + c8 * 8;
            *(short8*)&KV[row][c8 * 8] = *(const short8*)gp;
        }
        __syncthreads();
        short8 af[3], bf[3];
        #pragma unroll
        for (int t = 0; t < 3; ++t) {
            #pragma unroll
            for (int j = 0; j < 8; ++j) {
                af[t][j] = (short)KV[q8 + j][w * 48 + t * 16 + r15];
                bf[t][j] = (short)KV[q8 + j][192 + w * 48 + t * 16 + r15];
            }
        }
        #pragma unroll
        for (int i = 0; i < 3; ++i) {
            #pragma unroll
            for (int j = 0; j < 3; ++j)
                kv[i][j] = __builtin_amdgcn_mfma_f32_16x16x32_bf16(af[i], bf[j], kv[i][j], 0, 0, 0);
            kv[i][3] = __builtin_amdgcn_mfma_f32_16x16x32_bf16(af[i], onesf, kv[i][3], 0, 0, 0);
        }
        __syncthreads();
    }

    #pragma unroll
    for (int i = 0; i < 3; ++i) {
        #pragma unroll
        for (int j = 0; j < 3; ++j)
            #pragma unroll
            for (int r = 0; r < 4; ++r)
                kvs[w][j * 16 + r15][i * 16 + q * 4 + r] = f2b(kv[i][j][r]);
        if (r15 == 0)
            #pragma unroll
            for (int r = 0; r < 4; ++r)
                kvs[w][48][i * 16 + q * 4 + r] = f2b(kv[i][3][r]);
    }

    short8 bkv[2][4];
    #pragma unroll
    for (int kk = 0; kk < 2; ++kk)
        #pragma unroll
        for (int t = 0; t < 4; ++t)
            bkv[kk][t] = *(const short8*)&kvs[w][t * 16 + r15][kk * 32 + q8];

    for (int mt = 0; mt < N / 16; ++mt) {
        float4v o[4];
        #pragma unroll
        for (int t = 0; t < 4; ++t) o[t] = (float4v){0.f, 0.f, 0.f, 0.f};
        #pragma unroll
        for (int kk = 0; kk < 2; ++kk) {
            const unsigned short* qp = QKV + ((size_t)(base + (size_t)(mt * 16 + r15) * MSTR)) * 576
                                       + w * 48 + kk * 32 + q8;
            short8 aq = *(const short8*)qp;
            #pragma unroll
            for (int t = 0; t < 4; ++t)
                o[t] = __builtin_amdgcn_mfma_f32_16x16x32_bf16(aq, bkv[kk][t], o[t], 0, 0, 0);
        }
        #pragma unroll
        for (int r = 0; r < 4; ++r) {
            float den = __shfl(o[3][r], q << 4);
            float z = 1.0f / (den + 1e-6f);
            int n = mt * 16 + q * 4 + r;
            unsigned short* op = O + ((size_t)(base + (size_t)n * MSTR)) * 192 + w * 48;
            #pragma unroll
            for (int t = 0; t < 3; ++t)
                op[t * 16 + r15] = f2b(o[t][r] * z);
        }
    }
}

__global__ __launch_bounds__(256) void final_kernel(const float* __restrict__ X, const float* __restrict__ pw_w,
                                                    const float* __restrict__ pw_b, float* __restrict__ out) {
    int wave = threadIdx.x >> 6;
    int lane = threadIdx.x & 63;
    int p = blockIdx.x * 4 + wave;
    const float* xp = X + (size_t)p * CCH;
    float s = xp[lane] * pw_w[lane] + xp[lane + 64] * pw_w[lane + 64] + xp[lane + 128] * pw_w[lane + 128];
    #pragma unroll
    for (int off = 32; off; off >>= 1) s += __shfl_xor(s, off, 64);
    if (lane == 0) {
        float o = s + pw_b[0];
        float e = expf(o);
        out[p] = 1.0f - 1.0f / (2.0f + e);
    }
}

extern "C" void kernel_launch(void* const* d_in, const int* in_sizes, int n_in,
                              void* d_out, int out_size, void* d_ws, size_t ws_size,
                              hipStream_t stream) {
    const int*   tokens = (const int*)  d_in[0];
    const float* emb    = (const float*)d_in[1];
    const float* proj_w = (const float*)d_in[2];
    const float* proj_b = (const float*)d_in[3];
    const float* ln_g   = (const float*)d_in[4];
    const float* ln_b   = (const float*)d_in[5];
    const float* wq     = (const float*)d_in[6];
    const float* wk     = (const float*)d_in[7];
    const float* wv     = (const float*)d_in[8];
    const float* wo     = (const float*)d_in[9];
    const float* bq     = (const float*)d_in[10];
    const float* bk     = (const float*)d_in[11];
    const float* bv     = (const float*)d_in[12];
    const float* bo     = (const float*)d_in[13];
    const float* ffn_w1 = (const float*)d_in[14];
    const float* ffn_b1 = (const float*)d_in[15];
    const float* ffn_w2 = (const float*)d_in[16];
    const float* ffn_b2 = (const float*)d_in[17];
    const float* pw_w   = (const float*)d_in[18];
    const float* pw_b   = (const float*)d_in[19];

    float* X             = (float*)d_ws;
    unsigned short* Hb   = (unsigned short*)(X + BUF);
    unsigned short* Ho   = Hb + BUF;
    unsigned short* QKVb = Ho + BUF;                     // NP x 576
    unsigned short* hid  = QKVb + 3 * BUF;               // tmp (proj only)
    unsigned short* Eg   = hid + 4 * BUF;
    unsigned short* wqkvb = Eg + (size_t)NP * 64;
    const int QKVSZ = NBLK * 2 * 576 * CCH;
    const int WSZ   = NBLK * 2 * CCH * CCH;
    const int FSZ   = NBLK * 768 * CCH;
    unsigned short* wob = wqkvb + QKVSZ;
    unsigned short* w1b = wob + WSZ;
    unsigned short* w2b = w1b + FSZ;
    unsigned short* pjb = w2b + FSZ;
    float* bqkvb = (float*)(pjb + 12288 + 32);
    float* Xt = (float*)hid;

    wqkv_concat<<<QKVSZ / 256, 256, 0, stream>>>(wq, wk, wv, wqkvb);
    bqkv_concat<<<27, 256, 0, stream>>>(bq, bk, bv, bqkvb);
    convert_kernel<<<(WSZ + 255) / 256, 256, 0, stream>>>(wo, wob, WSZ);
    convert_kernel<<<(FSZ + 255) / 256, 256, 0, stream>>>(ffn_w1, w1b, FSZ);
    convert_kernel<<<(FSZ + 255) / 256, 256, 0, stream>>>(ffn_w2, w2b, FSZ);
    convert_kernel<<<48, 256, 0, stream>>>(proj_w, pjb, 12288);

    gather_kernel<<<NP * 64 / 256, 256, 0, stream>>>(tokens, emb, Eg);
    mm192<64, 0, 1><<<dim3(1, NP / 64), 256, 0, stream>>>(Eg, pjb, proj_b, nullptr, Xt,
                                                          nullptr, nullptr, nullptr, nullptr, NP, CCH, 64);
    rotary_ln_kernel<<<NP / 4, 256, 0, stream>>>(Xt, X, Hb, ln_g, ln_b);

    for (int i = 0; i < NBLK; ++i) {
        for (int att = 0; att < 2; ++att) {
            size_t wi = (size_t)(i * 2 + att);
            const unsigned short* wqkvi = wqkvb + wi * 576 * CCH;
            const float* bqkvi = bqkvb + wi * 576;
            const unsigned short* woi = wob + wi * CCH * CCH;
            const float* boi = bo + wi * CCH;
            const float* gn  = ln_g + (size_t)(i * 3 + att + 1) * CCH;
            const float* bnn = ln_b + (size_t)(i * 3 + att + 1) * CCH;
            mm192<128, 4, 0><<<dim3(3, NP / 128), 256, 0, stream>>>(Hb, wqkvi, bqkvi, QKVb, nullptr,
                                                                    nullptr, nullptr, nullptr, nullptr, NP, 576, CCH);
            if (att == 0) attn_axial<LL, 1><<<BB * SS, 256, 0, stream>>>(QKVb, Ho);
            else          attn_axial<SS, LL><<<BB * LL, 256, 0, stream>>>(QKVb, Ho);
            mm192<64, 0, 2><<<dim3(1, NP / 64), 256, 0, stream>>>(Ho, woi, boi, nullptr, nullptr,
                                                                  X, Hb, gn, bnn, NP, CCH, CCH);
        }
        const unsigned short* w1 = w1b + (size_t)i * 768 * CCH;
        const unsigned short* w2 = w2b + (size_t)i * CCH * 768;
        const float* b1 = ffn_b1 + (size_t)i * 768;
        const float* b2 = ffn_b2 + (size_t)i * CCH;
        if (i < NBLK - 1) {
            const float* gn  = ln_g + (size_t)((i + 1) * 3) * CCH;
            const float* bnn = ln_b + (size_t)((i + 1) * 3) * CCH;
            ffn_fused<false><<<NP / 64, 256, 0, stream>>>(Hb, w1, b1, w2, b2, X, Hb, gn, bnn);
        } else {
            ffn_fused<true><<<NP / 64, 256, 0, stream>>>(Hb, w1, b1, w2, b2, X, nullptr, nullptr, nullptr);
        }
    }
    final_kernel<<<NP / 4, 256, 0, stream>>>(X, pw_w, pw_b, (float*)d_out);
}